// Round 5
// baseline (668.578 us; speedup 1.0000x reference)
//
#include <hip/hip_runtime.h>
#include <math.h>

#define D 64
#define GN 128       // nodes per gemm_update block
#define BSHIFT 7     // bucket = dst >> 7  (128 nodes per bucket)
#define BN 128       // nodes per bucket
#define MAXNB 1024   // scan_buckets capacity (N <= 131072)

// Detect whether edge_index is int64 (odd int32 words are zero high-halves)
// or int32 (odd words are random node ids).
__global__ void detect_idx64(const int* __restrict__ ei, int* __restrict__ flag) {
    int v = ei[2 * threadIdx.x + 1];
    unsigned long long b = __ballot(v != 0);
    if (threadIdx.x == 0) flag[0] = (b == 0ULL) ? 1 : 0;
}

// ---------------- bucketed CSR build ----------------

// Per-block LDS histogram of dst>>BSHIFT, merged into global bucketCount.
__global__ __launch_bounds__(256) void bucket_hist(
        const void* __restrict__ eidx, const int* __restrict__ flagp,
        int* __restrict__ bucketCount, int nE, int nb) {
    __shared__ int h[MAXNB];
    const bool idx64 = (*flagp != 0);
    const int* __restrict__ ei32 = (const int*)eidx;
    const long long* __restrict__ ei64 = (const long long*)eidx;
    for (int i = threadIdx.x; i < nb; i += 256) h[i] = 0;
    __syncthreads();
    int i = blockIdx.x * blockDim.x + threadIdx.x;
    int stride = gridDim.x * blockDim.x;
    for (int e = i; e < nE; e += stride) {
        int d = idx64 ? (int)ei64[e + nE] : ei32[e + nE];
        atomicAdd(&h[d >> BSHIFT], 1);
    }
    __syncthreads();
    for (int i2 = threadIdx.x; i2 < nb; i2 += 256)
        if (h[i2]) atomicAdd(&bucketCount[i2], h[i2]);
}

// Single-block exclusive scan of bucketCount (nb <= MAXNB = 256 thr x 4).
// Writes bucketBase[0..nb] and initializes bucketCursor = bucketBase.
__global__ __launch_bounds__(256) void scan_buckets(
        const int* __restrict__ bc, int* __restrict__ bbase,
        int* __restrict__ bcur, int nb) {
    __shared__ int wtot[4];
    int tid = threadIdx.x, lane = tid & 63, wid = tid >> 6;
    int base = tid * 4;
    int v0 = (base + 0 < nb) ? bc[base + 0] : 0;
    int v1 = (base + 1 < nb) ? bc[base + 1] : 0;
    int v2 = (base + 2 < nb) ? bc[base + 2] : 0;
    int v3 = (base + 3 < nb) ? bc[base + 3] : 0;
    int t = v0 + v1 + v2 + v3;
    int x = t;
    #pragma unroll
    for (int off = 1; off < 64; off <<= 1) { int y = __shfl_up(x, off, 64); if (lane >= off) x += y; }
    if (lane == 63) wtot[wid] = x;
    __syncthreads();
    int woff = 0;
    for (int w = 0; w < wid; ++w) woff += wtot[w];
    int e = woff + x - t;
    if (base + 0 < nb) { bbase[base + 0] = e; bcur[base + 0] = e; } e += v0;
    if (base + 1 < nb) { bbase[base + 1] = e; bcur[base + 1] = e; } e += v1;
    if (base + 2 < nb) { bbase[base + 2] = e; bcur[base + 2] = e; } e += v2;
    if (base + 3 < nb) { bbase[base + 3] = e; bcur[base + 3] = e; }
    if (tid == 255) bbase[nb] = woff + x;   // total = E
}

// Scatter (src, dst&127) 8-B pairs into bucket regions. Frontier of ~nb cache
// lines -> good write locality vs the old fully-random 4-B scatter.
__global__ __launch_bounds__(256) void bucket_fill(
        const void* __restrict__ eidx, const int* __restrict__ flagp,
        int* __restrict__ bcur, unsigned long long* __restrict__ pairs, int nE) {
    const bool idx64 = (*flagp != 0);
    const int* __restrict__ ei32 = (const int*)eidx;
    const long long* __restrict__ ei64 = (const long long*)eidx;
    int i = blockIdx.x * blockDim.x + threadIdx.x;
    int stride = gridDim.x * blockDim.x;
    for (int e = i; e < nE; e += stride) {
        int s, d;
        if (idx64) { s = (int)ei64[e]; d = (int)ei64[e + nE]; }
        else       { s = ei32[e];      d = ei32[e + nE]; }
        int b = d >> BSHIFT;
        int pos = atomicAdd(&bcur[b], 1);
        pairs[pos] = (unsigned long long)(unsigned)s
                   | ((unsigned long long)(unsigned)(d & (BN - 1)) << 32);
    }
}

// One block per bucket: local count + scan in LDS, emit rowStart (coalesced)
// and srcs (contiguous 16-KB bucket region).
__global__ __launch_bounds__(256) void bucket_to_csr(
        const unsigned long long* __restrict__ pairs,
        const int* __restrict__ bbase, const int* __restrict__ bcount,
        int* __restrict__ rowStart, int* __restrict__ srcs,
        int N, int nb, int nE) {
    __shared__ int lcnt[BN];
    __shared__ int lcur[BN];
    const int b = blockIdx.x;
    const int base = bbase[b];
    const int cnt  = bcount[b];
    const int tid = threadIdx.x;
    for (int i = tid; i < BN; i += 256) lcnt[i] = 0;
    __syncthreads();
    for (int i = tid; i < cnt; i += 256) {
        unsigned long long p = pairs[base + i];
        atomicAdd(&lcnt[(int)(p >> 32)], 1);
    }
    __syncthreads();
    // exclusive scan of lcnt[0..127] by wave 0 (2 elems/lane)
    if (tid < 64) {
        int v0 = lcnt[2 * tid], v1 = lcnt[2 * tid + 1];
        int t = v0 + v1, x = t;
        #pragma unroll
        for (int off = 1; off < 64; off <<= 1) { int y = __shfl_up(x, off, 64); if (tid >= off) x += y; }
        int excl = x - t;
        lcur[2 * tid]     = excl;
        lcur[2 * tid + 1] = excl + v0;
    }
    __syncthreads();
    const int node0 = b * BN;
    for (int i = tid; i < BN; i += 256) {
        int n = node0 + i;
        if (n < N) rowStart[n] = base + lcur[i];
    }
    if (b == nb - 1 && tid == 0) rowStart[N] = nE;
    __syncthreads();   // rowStart reads of lcur done before scatter mutates it
    for (int i = tid; i < cnt; i += 256) {
        unsigned long long p = pairs[base + i];
        int dl = (int)(p >> 32);
        int pos = atomicAdd(&lcur[dl], 1);
        srcs[base + pos] = (int)(unsigned)p;
    }
}

// ---------------- layer stage 1: gather + mean (latency-optimized) ---------
__global__ __launch_bounds__(256) void gather_mean(
        const float* __restrict__ x,
        const int* __restrict__ rowStart,
        const int* __restrict__ srcs,
        float* __restrict__ agg,
        int nNodes) {
    const int tid = threadIdx.x;
    const int gl = tid & 15;          // lane within group (feature chunk)
    const int grp = tid >> 4;         // group within block (node)
    const int node = blockIdx.x * 16 + grp;
    if (node >= nNodes) return;
    const int r0 = rowStart[node], r1 = rowStart[node + 1];
    float ax = 0.f, ay = 0.f, az = 0.f, aw = 0.f;
    int j = r0;
    for (; j + 2 <= r1; j += 2) {
        int s0 = srcs[j], s1 = srcs[j + 1];
        float4 v0 = *(const float4*)&x[(size_t)s0 * D + gl * 4];
        float4 v1 = *(const float4*)&x[(size_t)s1 * D + gl * 4];
        ax += v0.x; ay += v0.y; az += v0.z; aw += v0.w;
        ax += v1.x; ay += v1.y; az += v1.z; aw += v1.w;
    }
    if (j < r1) {
        int s = srcs[j];
        float4 v = *(const float4*)&x[(size_t)s * D + gl * 4];
        ax += v.x; ay += v.y; az += v.z; aw += v.w;
    }
    const float inv = 1.0f / fmaxf((float)(r1 - r0), 1.0f);
    float4 o; o.x = ax * inv; o.y = ay * inv; o.z = az * inv; o.w = aw * inv;
    *(float4*)&agg[(size_t)node * D + gl * 4] = o;
}

// ---------------- layer stage 2: register-blocked f32 GEMM update ----------
__global__ __launch_bounds__(256) void gemm_update(
        const float* __restrict__ agg,
        const float* __restrict__ xin,
        const float* __restrict__ wl,
        const float* __restrict__ bl,
        const float* __restrict__ wr,
        float* __restrict__ xout,
        int nNodes, int mode) {
    __shared__ float sA[D][GN + 4];
    __shared__ float sW[D][D + 4];
    const int tid = threadIdx.x;
    const int fx = tid & 15, nx = tid >> 4;
    const int f0 = fx * 4, n0 = nx * 8;
    const int nb = blockIdx.x * GN;

    float c[8][4];
    #pragma unroll
    for (int i = 0; i < 8; ++i)
        #pragma unroll
        for (int j = 0; j < 4; ++j) c[i][j] = 0.f;

    #pragma unroll
    for (int phase = 0; phase < 2; ++phase) {
        const float* __restrict__ gA = phase ? xin : agg;
        const float* __restrict__ gW = phase ? wr : wl;
        if (phase) __syncthreads();
        for (int i = tid; i < GN * D; i += 256) {
            int n = i >> 6, k = i & 63;
            int gn = nb + n;
            sA[k][n] = (gn < nNodes) ? gA[(size_t)gn * D + k] : 0.f;
        }
        for (int i = tid; i < D * D; i += 256) {
            int f = i >> 6, k = i & 63;
            sW[k][f] = gW[i];
        }
        __syncthreads();
        #pragma unroll 8
        for (int k = 0; k < D; ++k) {
            float4 a0 = *(const float4*)&sA[k][n0];
            float4 a1 = *(const float4*)&sA[k][n0 + 4];
            float4 w  = *(const float4*)&sW[k][f0];
            float av[8] = {a0.x, a0.y, a0.z, a0.w, a1.x, a1.y, a1.z, a1.w};
            float wv[4] = {w.x, w.y, w.z, w.w};
            #pragma unroll
            for (int i = 0; i < 8; ++i)
                #pragma unroll
                for (int j = 0; j < 4; ++j)
                    c[i][j] = fmaf(av[i], wv[j], c[i][j]);
        }
    }

    float4 bv = *(const float4*)&bl[f0];
    float blv[4] = {bv.x, bv.y, bv.z, bv.w};
    #pragma unroll
    for (int i = 0; i < 8; ++i) {
        int gn = nb + n0 + i;
        float o[4];
        #pragma unroll
        for (int j = 0; j < 4; ++j) o[j] = c[i][j] + blv[j];
        if (mode == 0) {
            #pragma unroll
            for (int j = 0; j < 4; ++j) o[j] = fmaxf(o[j], 0.f);
        } else {
            float ss = o[0]*o[0] + o[1]*o[1] + o[2]*o[2] + o[3]*o[3];
            #pragma unroll
            for (int off = 8; off >= 1; off >>= 1) ss += __shfl_xor(ss, off, 16);
            float inv = 1.0f / fmaxf(sqrtf(ss), 1e-12f);
            #pragma unroll
            for (int j = 0; j < 4; ++j) o[j] *= inv;
        }
        if (gn < nNodes) {
            float4 ov; ov.x = o[0]; ov.y = o[1]; ov.z = o[2]; ov.w = o[3];
            *(float4*)&xout[(size_t)gn * D + f0] = ov;
        }
    }
}

// ---------------- fallback: atomic scatter path (round-1, known-correct) ----

__global__ __launch_bounds__(256) void sage_scatter(
        const float* __restrict__ x,
        const void* __restrict__ eidx,
        const int* __restrict__ flagp,
        float* __restrict__ agg,
        float* __restrict__ deg,
        int nE, int doDeg) {
    const bool idx64 = (*flagp != 0);
    const int lane = threadIdx.x & 63;
    int wave = (int)((blockIdx.x * blockDim.x + threadIdx.x) >> 6);
    const int waveStride = (int)((gridDim.x * blockDim.x) >> 6);
    const int* __restrict__ ei32 = (const int*)eidx;
    const long long* __restrict__ ei64 = (const long long*)eidx;
    for (int e = wave; e < nE; e += waveStride) {
        int s, d;
        if (idx64) { s = (int)ei64[e]; d = (int)ei64[e + nE]; }
        else       { s = ei32[e];      d = ei32[e + nE]; }
        atomicAdd(&agg[(size_t)d * D + lane], x[(size_t)s * D + lane]);
        if (doDeg && lane == 0) atomicAdd(&deg[d], 1.0f);
    }
}

__global__ __launch_bounds__(256) void sage_update(
        const float* __restrict__ xin,
        const float* __restrict__ agg,
        const float* __restrict__ deg,
        const float* __restrict__ wl,
        const float* __restrict__ bl,
        const float* __restrict__ wr,
        float* __restrict__ xout,
        int nNodes, int mode) {
    __shared__ float wlT[D * D];
    __shared__ float wrT[D * D];
    __shared__ float rowA[4][D];
    __shared__ float rowX[4][D];
    for (int i = threadIdx.x; i < D * D; i += blockDim.x) {
        int f = i >> 6, k = i & 63;
        wlT[k * D + f] = wl[i];
        wrT[k * D + f] = wr[i];
    }
    __syncthreads();
    const int lane = threadIdx.x & 63;
    const int wid = threadIdx.x >> 6;
    const float blv = bl[lane];
    for (int node = blockIdx.x * 4 + wid; node < nNodes; node += gridDim.x * 4) {
        float dg = fmaxf(deg[node], 1.0f);
        float a  = agg[(size_t)node * D + lane] / dg;
        float xv = xin[(size_t)node * D + lane];
        rowA[wid][lane] = a;
        rowX[wid][lane] = xv;
        float acc = blv;
        #pragma unroll
        for (int k = 0; k < D; ++k) {
            acc = fmaf(rowA[wid][k], wlT[k * D + lane], acc);
            acc = fmaf(rowX[wid][k], wrT[k * D + lane], acc);
        }
        if (mode == 0) {
            xout[(size_t)node * D + lane] = fmaxf(acc, 0.0f);
        } else {
            float ss = acc * acc;
            #pragma unroll
            for (int off = 32; off >= 1; off >>= 1) ss += __shfl_xor(ss, off, 64);
            xout[(size_t)node * D + lane] = acc / fmaxf(sqrtf(ss), 1e-12f);
        }
    }
}

extern "C" void kernel_launch(void* const* d_in, const int* in_sizes, int n_in,
                              void* d_out, int out_size, void* d_ws, size_t ws_size,
                              hipStream_t stream) {
    const float* x   = (const float*)d_in[0];
    const float* wl0 = (const float*)d_in[1];
    const float* bl0 = (const float*)d_in[2];
    const float* wr0 = (const float*)d_in[3];
    const float* wl1 = (const float*)d_in[4];
    const float* bl1 = (const float*)d_in[5];
    const float* wr1 = (const float*)d_in[6];
    const void*  ei  = d_in[7];
    float* out = (float*)d_out;

    const int N = in_sizes[0] / D;
    const int E = in_sizes[7] / 2;
    const int NB = (N + BN - 1) / BN;   // 782 for N=100000

    char* ws = (char*)d_ws;
    size_t off = 0;
    auto alloc = [&](size_t bytes) { void* p = ws + off; off = (off + bytes + 255) & ~(size_t)255; return p; };

    // layout: flag, bucketCount, bucketBase, bucketCursor, rowStart, srcs, x1,
    //         sharedRegion = max(pairs E*8, agg N*D*4)  (pairs dead before agg live)
    size_t shared_bytes = (size_t)E * 8;
    if ((size_t)N * D * 4 > shared_bytes) shared_bytes = (size_t)N * D * 4;
    size_t need = 0;
    {
        size_t o = 0;
        auto sim = [&](size_t b) { o = (o + b + 255) & ~(size_t)255; };
        sim(4); sim((size_t)NB * 4); sim(((size_t)NB + 1) * 4); sim((size_t)NB * 4);
        sim(((size_t)N + 1) * 4); sim((size_t)E * 4); sim((size_t)N * D * 4);
        sim(shared_bytes);
        need = o;
    }

    if (ws_size >= need && NB <= MAXNB) {
        int* flag         = (int*)alloc(4);
        int* bucketCount  = (int*)alloc((size_t)NB * 4);
        int* bucketBase   = (int*)alloc(((size_t)NB + 1) * 4);
        int* bucketCursor = (int*)alloc((size_t)NB * 4);
        int* rowStart     = (int*)alloc(((size_t)N + 1) * 4);
        int* srcs         = (int*)alloc((size_t)E * 4);
        float* x1         = (float*)alloc((size_t)N * D * 4);
        void* shared      = alloc(shared_bytes);
        unsigned long long* pairs = (unsigned long long*)shared;
        float* agg        = (float*)shared;

        detect_idx64<<<1, 64, 0, stream>>>((const int*)ei, flag);
        hipMemsetAsync(bucketCount, 0, (size_t)NB * 4, stream);
        bucket_hist<<<256, 256, 0, stream>>>(ei, flag, bucketCount, E, NB);
        scan_buckets<<<1, 256, 0, stream>>>(bucketCount, bucketBase, bucketCursor, NB);
        bucket_fill<<<2048, 256, 0, stream>>>(ei, flag, bucketCursor, pairs, E);
        bucket_to_csr<<<NB, 256, 0, stream>>>(pairs, bucketBase, bucketCount,
                                              rowStart, srcs, N, NB, E);

        const int gGather = (N + 15) / 16;
        const int gGemm   = (N + GN - 1) / GN;
        gather_mean<<<gGather, 256, 0, stream>>>(x, rowStart, srcs, agg, N);
        gemm_update<<<gGemm, 256, 0, stream>>>(agg, x, wl0, bl0, wr0, x1, N, 0);
        gather_mean<<<gGather, 256, 0, stream>>>(x1, rowStart, srcs, agg, N);
        gemm_update<<<gGemm, 256, 0, stream>>>(agg, x1, wl1, bl1, wr1, out, N, 1);
    } else {
        // fallback: round-1 scatter path (~26 MB ws)
        int*   flag = (int*)alloc(4);
        float* deg  = (float*)alloc((size_t)N * 4);
        float* agg  = (float*)alloc((size_t)N * D * 4);
        float* x1   = out;  // safe: sage_update reads only its own row of xin

        detect_idx64<<<1, 64, 0, stream>>>((const int*)ei, flag);
        hipMemsetAsync(deg, 0, ((size_t)N + (size_t)N * D) * 4, stream);
        sage_scatter<<<4096, 256, 0, stream>>>(x, ei, flag, agg, deg, E, 1);
        sage_update<<<2048, 256, 0, stream>>>(x, agg, deg, wl0, bl0, wr0, x1, N, 0);
        hipMemsetAsync(agg, 0, (size_t)N * D * 4, stream);
        sage_scatter<<<4096, 256, 0, stream>>>(x1, ei, flag, agg, deg, E, 0);
        sage_update<<<2048, 256, 0, stream>>>(x1, agg, deg, wl1, bl1, wr1, out, N, 1);
    }
}

// Round 6
// 376.695 us; speedup vs baseline: 1.7749x; 1.7749x over previous
//
#include <hip/hip_runtime.h>
#include <math.h>

#define D 64
#define GN 128        // nodes per gemm_update block
#define BSHIFT 10     // bucket = dst >> 10 (1024 nodes per bucket)
#define BN 1024       // nodes per bucket
#define MAXB 128      // max buckets (N <= 131072)
#define NBLK 512      // partition blocks for hist2d/fill2
#define NBLK_LOG 9

// Detect whether edge_index is int64 (odd int32 words are zero high-halves)
// or int32 (odd words are random node ids).
__global__ void detect_idx64(const int* __restrict__ ei, int* __restrict__ flag) {
    int v = ei[2 * threadIdx.x + 1];
    unsigned long long b = __ballot(v != 0);
    if (threadIdx.x == 0) flag[0] = (b == 0ULL) ? 1 : 0;
}

// ---------------- deterministic counting-sort CSR build ----------------

// Each block owns edges [blk*epb, (blk+1)*epb): LDS histogram of dst>>BSHIFT,
// then H[bucket*NBLK + blk] = count. No global atomics.
__global__ __launch_bounds__(256) void hist2d(
        const void* __restrict__ eidx, const int* __restrict__ flagp,
        int* __restrict__ H, int nE, int nb, int epb) {
    __shared__ int h[MAXB];
    const bool idx64 = (*flagp != 0);
    const int* __restrict__ ei32 = (const int*)eidx;
    const long long* __restrict__ ei64 = (const long long*)eidx;
    for (int i = threadIdx.x; i < nb; i += 256) h[i] = 0;
    __syncthreads();
    const int e0 = blockIdx.x * epb;
    const int e1 = min(e0 + epb, nE);
    for (int e = e0 + threadIdx.x; e < e1; e += 256) {
        int d = idx64 ? (int)ei64[e + nE] : ei32[e + nE];
        atomicAdd(&h[d >> BSHIFT], 1);
    }
    __syncthreads();
    for (int i = threadIdx.x; i < nb; i += 256)
        H[(i << NBLK_LOG) + blockIdx.x] = h[i];
}

// Single-block exclusive scan of H[0..nb*NBLK) in bucket-major order.
// Also emits bbase[b] (bucket start offsets) and bbase[nb] = E.
__global__ __launch_bounds__(1024) void scan_matrix(
        int* __restrict__ H, int* __restrict__ bbase, int nb, int nE) {
    __shared__ int wtot[16];
    const int total = nb << NBLK_LOG;
    const int tid = threadIdx.x, lane = tid & 63, wid = tid >> 6;
    const int per = (total + 1023) >> 10;
    const int start = tid * per;
    const int end = min(start + per, total);
    int s = 0;
    for (int i = start; i < end; ++i) s += H[i];
    int x = s;
    #pragma unroll
    for (int off = 1; off < 64; off <<= 1) { int y = __shfl_up(x, off, 64); if (lane >= off) x += y; }
    if (lane == 63) wtot[wid] = x;
    __syncthreads();
    if (tid == 0) {
        int r = 0;
        for (int w = 0; w < 16; ++w) { int t = wtot[w]; wtot[w] = r; r += t; }
    }
    __syncthreads();
    int run = wtot[wid] + (x - s);
    for (int i = start; i < end; ++i) {
        int v = H[i];
        H[i] = run;
        if ((i & (NBLK - 1)) == 0) bbase[i >> NBLK_LOG] = run;
        run += v;
    }
    if (tid == 0) bbase[nb] = nE;
}

// Re-read the same edge range; LDS cursors seeded from scanned H give each
// block a private, mostly-sequential write window per bucket. No global atomics.
__global__ __launch_bounds__(256) void fill2(
        const void* __restrict__ eidx, const int* __restrict__ flagp,
        const int* __restrict__ H, unsigned long long* __restrict__ pairs,
        int nE, int nb, int epb) {
    __shared__ int cur[MAXB];
    const bool idx64 = (*flagp != 0);
    const int* __restrict__ ei32 = (const int*)eidx;
    const long long* __restrict__ ei64 = (const long long*)eidx;
    for (int i = threadIdx.x; i < nb; i += 256)
        cur[i] = H[(i << NBLK_LOG) + blockIdx.x];
    __syncthreads();
    const int e0 = blockIdx.x * epb;
    const int e1 = min(e0 + epb, nE);
    for (int e = e0 + threadIdx.x; e < e1; e += 256) {
        int s, d;
        if (idx64) { s = (int)ei64[e]; d = (int)ei64[e + nE]; }
        else       { s = ei32[e];      d = ei32[e + nE]; }
        int pos = atomicAdd(&cur[d >> BSHIFT], 1);
        pairs[pos] = (unsigned long long)(unsigned)s
                   | ((unsigned long long)(unsigned)(d & (BN - 1)) << 32);
    }
}

// One block per bucket: LDS count + block scan over BN local nodes, emit
// rowStart (coalesced) and dst-sorted srcs (within the bucket's region).
__global__ __launch_bounds__(1024) void bucket_to_csr(
        const unsigned long long* __restrict__ pairs,
        const int* __restrict__ bbase,
        int* __restrict__ rowStart, int* __restrict__ srcs,
        int N, int nb, int nE) {
    __shared__ int lcnt[BN];
    __shared__ int lcur[BN];
    __shared__ int wtot[16];
    const int b = blockIdx.x;
    const int base = bbase[b];
    const int cnt  = bbase[b + 1] - base;
    const int tid = threadIdx.x, lane = tid & 63, wid = tid >> 6;
    lcnt[tid] = 0;
    __syncthreads();
    for (int i = tid; i < cnt; i += 1024)
        atomicAdd(&lcnt[(int)(pairs[base + i] >> 32)], 1);
    __syncthreads();
    int v = lcnt[tid];
    int x = v;
    #pragma unroll
    for (int off = 1; off < 64; off <<= 1) { int y = __shfl_up(x, off, 64); if (lane >= off) x += y; }
    if (lane == 63) wtot[wid] = x;
    __syncthreads();
    if (tid == 0) {
        int r = 0;
        for (int w = 0; w < 16; ++w) { int t = wtot[w]; wtot[w] = r; r += t; }
    }
    __syncthreads();
    int excl = wtot[wid] + (x - v);
    lcur[tid] = excl;
    int node = b * BN + tid;
    if (node < N) rowStart[node] = base + excl;
    if (b == nb - 1 && tid == 0) rowStart[N] = nE;
    __syncthreads();
    for (int i = tid; i < cnt; i += 1024) {
        unsigned long long p = pairs[base + i];
        int pos = atomicAdd(&lcur[(int)(p >> 32)], 1);
        srcs[base + pos] = (int)(unsigned)p;
    }
}

// ---------------- layer stage 1: gather + mean (latency-optimized) ---------
__global__ __launch_bounds__(256) void gather_mean(
        const float* __restrict__ x,
        const int* __restrict__ rowStart,
        const int* __restrict__ srcs,
        float* __restrict__ agg,
        int nNodes) {
    const int tid = threadIdx.x;
    const int gl = tid & 15;          // lane within group (feature chunk)
    const int grp = tid >> 4;         // group within block (node)
    const int node = blockIdx.x * 16 + grp;
    if (node >= nNodes) return;
    const int r0 = rowStart[node], r1 = rowStart[node + 1];
    float ax = 0.f, ay = 0.f, az = 0.f, aw = 0.f;
    int j = r0;
    for (; j + 2 <= r1; j += 2) {
        int s0 = srcs[j], s1 = srcs[j + 1];
        float4 v0 = *(const float4*)&x[(size_t)s0 * D + gl * 4];
        float4 v1 = *(const float4*)&x[(size_t)s1 * D + gl * 4];
        ax += v0.x; ay += v0.y; az += v0.z; aw += v0.w;
        ax += v1.x; ay += v1.y; az += v1.z; aw += v1.w;
    }
    if (j < r1) {
        int s = srcs[j];
        float4 v = *(const float4*)&x[(size_t)s * D + gl * 4];
        ax += v.x; ay += v.y; az += v.z; aw += v.w;
    }
    const float inv = 1.0f / fmaxf((float)(r1 - r0), 1.0f);
    float4 o; o.x = ax * inv; o.y = ay * inv; o.z = az * inv; o.w = aw * inv;
    *(float4*)&agg[(size_t)node * D + gl * 4] = o;
}

// ---------------- layer stage 2: register-blocked f32 GEMM update ----------
__global__ __launch_bounds__(256) void gemm_update(
        const float* __restrict__ agg,
        const float* __restrict__ xin,
        const float* __restrict__ wl,
        const float* __restrict__ bl,
        const float* __restrict__ wr,
        float* __restrict__ xout,
        int nNodes, int mode) {
    __shared__ float sA[D][GN + 4];
    __shared__ float sW[D][D + 4];
    const int tid = threadIdx.x;
    const int fx = tid & 15, nx = tid >> 4;
    const int f0 = fx * 4, n0 = nx * 8;
    const int nb = blockIdx.x * GN;

    float c[8][4];
    #pragma unroll
    for (int i = 0; i < 8; ++i)
        #pragma unroll
        for (int j = 0; j < 4; ++j) c[i][j] = 0.f;

    #pragma unroll
    for (int phase = 0; phase < 2; ++phase) {
        const float* __restrict__ gA = phase ? xin : agg;
        const float* __restrict__ gW = phase ? wr : wl;
        if (phase) __syncthreads();
        for (int i = tid; i < GN * D; i += 256) {
            int n = i >> 6, k = i & 63;
            int gn = nb + n;
            sA[k][n] = (gn < nNodes) ? gA[(size_t)gn * D + k] : 0.f;
        }
        for (int i = tid; i < D * D; i += 256) {
            int f = i >> 6, k = i & 63;
            sW[k][f] = gW[i];
        }
        __syncthreads();
        #pragma unroll 8
        for (int k = 0; k < D; ++k) {
            float4 a0 = *(const float4*)&sA[k][n0];
            float4 a1 = *(const float4*)&sA[k][n0 + 4];
            float4 w  = *(const float4*)&sW[k][f0];
            float av[8] = {a0.x, a0.y, a0.z, a0.w, a1.x, a1.y, a1.z, a1.w};
            float wv[4] = {w.x, w.y, w.z, w.w};
            #pragma unroll
            for (int i = 0; i < 8; ++i)
                #pragma unroll
                for (int j = 0; j < 4; ++j)
                    c[i][j] = fmaf(av[i], wv[j], c[i][j]);
        }
    }

    float4 bv = *(const float4*)&bl[f0];
    float blv[4] = {bv.x, bv.y, bv.z, bv.w};
    #pragma unroll
    for (int i = 0; i < 8; ++i) {
        int gn = nb + n0 + i;
        float o[4];
        #pragma unroll
        for (int j = 0; j < 4; ++j) o[j] = c[i][j] + blv[j];
        if (mode == 0) {
            #pragma unroll
            for (int j = 0; j < 4; ++j) o[j] = fmaxf(o[j], 0.f);
        } else {
            float ss = o[0]*o[0] + o[1]*o[1] + o[2]*o[2] + o[3]*o[3];
            #pragma unroll
            for (int off = 8; off >= 1; off >>= 1) ss += __shfl_xor(ss, off, 16);
            float inv = 1.0f / fmaxf(sqrtf(ss), 1e-12f);
            #pragma unroll
            for (int j = 0; j < 4; ++j) o[j] *= inv;
        }
        if (gn < nNodes) {
            float4 ov; ov.x = o[0]; ov.y = o[1]; ov.z = o[2]; ov.w = o[3];
            *(float4*)&xout[(size_t)gn * D + f0] = ov;
        }
    }
}

// ---------------- fallback: atomic scatter path (round-1, known-correct) ----

__global__ __launch_bounds__(256) void sage_scatter(
        const float* __restrict__ x,
        const void* __restrict__ eidx,
        const int* __restrict__ flagp,
        float* __restrict__ agg,
        float* __restrict__ deg,
        int nE, int doDeg) {
    const bool idx64 = (*flagp != 0);
    const int lane = threadIdx.x & 63;
    int wave = (int)((blockIdx.x * blockDim.x + threadIdx.x) >> 6);
    const int waveStride = (int)((gridDim.x * blockDim.x) >> 6);
    const int* __restrict__ ei32 = (const int*)eidx;
    const long long* __restrict__ ei64 = (const long long*)eidx;
    for (int e = wave; e < nE; e += waveStride) {
        int s, d;
        if (idx64) { s = (int)ei64[e]; d = (int)ei64[e + nE]; }
        else       { s = ei32[e];      d = ei32[e + nE]; }
        atomicAdd(&agg[(size_t)d * D + lane], x[(size_t)s * D + lane]);
        if (doDeg && lane == 0) atomicAdd(&deg[d], 1.0f);
    }
}

__global__ __launch_bounds__(256) void sage_update(
        const float* __restrict__ xin,
        const float* __restrict__ agg,
        const float* __restrict__ deg,
        const float* __restrict__ wl,
        const float* __restrict__ bl,
        const float* __restrict__ wr,
        float* __restrict__ xout,
        int nNodes, int mode) {
    __shared__ float wlT[D * D];
    __shared__ float wrT[D * D];
    __shared__ float rowA[4][D];
    __shared__ float rowX[4][D];
    for (int i = threadIdx.x; i < D * D; i += blockDim.x) {
        int f = i >> 6, k = i & 63;
        wlT[k * D + f] = wl[i];
        wrT[k * D + f] = wr[i];
    }
    __syncthreads();
    const int lane = threadIdx.x & 63;
    const int wid = threadIdx.x >> 6;
    const float blv = bl[lane];
    for (int node = blockIdx.x * 4 + wid; node < nNodes; node += gridDim.x * 4) {
        float dg = fmaxf(deg[node], 1.0f);
        float a  = agg[(size_t)node * D + lane] / dg;
        float xv = xin[(size_t)node * D + lane];
        rowA[wid][lane] = a;
        rowX[wid][lane] = xv;
        float acc = blv;
        #pragma unroll
        for (int k = 0; k < D; ++k) {
            acc = fmaf(rowA[wid][k], wlT[k * D + lane], acc);
            acc = fmaf(rowX[wid][k], wrT[k * D + lane], acc);
        }
        if (mode == 0) {
            xout[(size_t)node * D + lane] = fmaxf(acc, 0.0f);
        } else {
            float ss = acc * acc;
            #pragma unroll
            for (int off = 32; off >= 1; off >>= 1) ss += __shfl_xor(ss, off, 64);
            xout[(size_t)node * D + lane] = acc / fmaxf(sqrtf(ss), 1e-12f);
        }
    }
}

extern "C" void kernel_launch(void* const* d_in, const int* in_sizes, int n_in,
                              void* d_out, int out_size, void* d_ws, size_t ws_size,
                              hipStream_t stream) {
    const float* x   = (const float*)d_in[0];
    const float* wl0 = (const float*)d_in[1];
    const float* bl0 = (const float*)d_in[2];
    const float* wr0 = (const float*)d_in[3];
    const float* wl1 = (const float*)d_in[4];
    const float* bl1 = (const float*)d_in[5];
    const float* wr1 = (const float*)d_in[6];
    const void*  ei  = d_in[7];
    float* out = (float*)d_out;

    const int N = in_sizes[0] / D;
    const int E = in_sizes[7] / 2;
    const int NB = (N + BN - 1) / BN;        // 98 for N=100000
    const int EPB = (E + NBLK - 1) / NBLK;   // edges per partition block

    char* ws = (char*)d_ws;
    size_t off = 0;
    auto alloc = [&](size_t bytes) { void* p = ws + off; off = (off + bytes + 255) & ~(size_t)255; return p; };

    size_t shared_bytes = (size_t)E * 8;
    if ((size_t)N * D * 4 > shared_bytes) shared_bytes = (size_t)N * D * 4;
    size_t need = 0;
    {
        size_t o = 0;
        auto sim = [&](size_t b) { o = (o + b + 255) & ~(size_t)255; };
        sim(4); sim(((size_t)MAXB << NBLK_LOG) * 4); sim(((size_t)MAXB + 1) * 4);
        sim(((size_t)N + 1) * 4); sim((size_t)E * 4); sim((size_t)N * D * 4);
        sim(shared_bytes);
        need = o;
    }

    if (ws_size >= need && NB <= MAXB) {
        int* flag     = (int*)alloc(4);
        int* H        = (int*)alloc(((size_t)MAXB << NBLK_LOG) * 4);
        int* bbase    = (int*)alloc(((size_t)MAXB + 1) * 4);
        int* rowStart = (int*)alloc(((size_t)N + 1) * 4);
        int* srcs     = (int*)alloc((size_t)E * 4);
        float* x1     = (float*)alloc((size_t)N * D * 4);
        void* shared  = alloc(shared_bytes);
        unsigned long long* pairs = (unsigned long long*)shared;
        float* agg    = (float*)shared;

        detect_idx64<<<1, 64, 0, stream>>>((const int*)ei, flag);
        hist2d<<<NBLK, 256, 0, stream>>>(ei, flag, H, E, NB, EPB);
        scan_matrix<<<1, 1024, 0, stream>>>(H, bbase, NB, E);
        fill2<<<NBLK, 256, 0, stream>>>(ei, flag, H, pairs, E, NB, EPB);
        bucket_to_csr<<<NB, 1024, 0, stream>>>(pairs, bbase, rowStart, srcs, N, NB, E);

        const int gGather = (N + 15) / 16;
        const int gGemm   = (N + GN - 1) / GN;
        gather_mean<<<gGather, 256, 0, stream>>>(x, rowStart, srcs, agg, N);
        gemm_update<<<gGemm, 256, 0, stream>>>(agg, x, wl0, bl0, wr0, x1, N, 0);
        gather_mean<<<gGather, 256, 0, stream>>>(x1, rowStart, srcs, agg, N);
        gemm_update<<<gGemm, 256, 0, stream>>>(agg, x1, wl1, bl1, wr1, out, N, 1);
    } else {
        // fallback: round-1 scatter path (~26 MB ws)
        int*   flag = (int*)alloc(4);
        float* deg  = (float*)alloc((size_t)N * 4);
        float* agg  = (float*)alloc((size_t)N * D * 4);
        float* x1   = out;  // safe: sage_update reads only its own row of xin

        detect_idx64<<<1, 64, 0, stream>>>((const int*)ei, flag);
        hipMemsetAsync(deg, 0, ((size_t)N + (size_t)N * D) * 4, stream);
        sage_scatter<<<4096, 256, 0, stream>>>(x, ei, flag, agg, deg, E, 1);
        sage_update<<<2048, 256, 0, stream>>>(x, agg, deg, wl0, bl0, wr0, x1, N, 0);
        hipMemsetAsync(agg, 0, (size_t)N * D * 4, stream);
        sage_scatter<<<4096, 256, 0, stream>>>(x1, ei, flag, agg, deg, E, 0);
        sage_update<<<2048, 256, 0, stream>>>(x1, agg, deg, wl1, bl1, wr1, out, N, 1);
    }
}

// Round 7
// 305.775 us; speedup vs baseline: 2.1865x; 1.2319x over previous
//
#include <hip/hip_runtime.h>
#include <math.h>

#define D 64
#define GN 128        // nodes per gemm_update block
#define BSHIFT 9      // bucket = dst >> 9 (512 nodes per bucket)
#define BN 512        // nodes per bucket
#define MAXB 256      // max buckets (N <= 131072)
#define NBLK 256      // partition blocks for hist2d/fill2
#define NBLK_LOG 8
#define SCHUNK 4096   // H entries per scan block (256 thr x 16)

// Detect whether edge_index is int64 (odd int32 words are zero high-halves)
// or int32 (odd words are random node ids).
__global__ void detect_idx64(const int* __restrict__ ei, int* __restrict__ flag) {
    int v = ei[2 * threadIdx.x + 1];
    unsigned long long b = __ballot(v != 0);
    if (threadIdx.x == 0) flag[0] = (b == 0ULL) ? 1 : 0;
}

// ---------------- deterministic counting-sort CSR build ----------------

// Each block owns edges [blk*epb, (blk+1)*epb): LDS histogram of dst>>BSHIFT,
// then H[bucket*NBLK + blk] = count. No global atomics.
__global__ __launch_bounds__(256) void hist2d(
        const void* __restrict__ eidx, const int* __restrict__ flagp,
        int* __restrict__ H, int nE, int nb, int epb) {
    __shared__ int h[MAXB];
    const bool idx64 = (*flagp != 0);
    const int* __restrict__ ei32 = (const int*)eidx;
    const long long* __restrict__ ei64 = (const long long*)eidx;
    for (int i = threadIdx.x; i < nb; i += 256) h[i] = 0;
    __syncthreads();
    const int e0 = blockIdx.x * epb;
    const int e1 = min(e0 + epb, nE);
    for (int e = e0 + threadIdx.x; e < e1; e += 256) {
        int d = idx64 ? (int)ei64[e + nE] : ei32[e + nE];
        atomicAdd(&h[d >> BSHIFT], 1);
    }
    __syncthreads();
    for (int i = threadIdx.x; i < nb; i += 256)
        H[(i << NBLK_LOG) + blockIdx.x] = h[i];
}

// Hierarchical exclusive scan of H[0..total) in bucket-major order.
// Stage 1: per-block sums.
__global__ __launch_bounds__(256) void scan_h_partial(
        const int* __restrict__ H, int* __restrict__ part, int total) {
    __shared__ int red[4];
    int base = blockIdx.x * SCHUNK + threadIdx.x * 16;
    int s = 0;
    #pragma unroll
    for (int k = 0; k < 16; ++k) { int i = base + k; if (i < total) s += H[i]; }
    #pragma unroll
    for (int off = 32; off >= 1; off >>= 1) s += __shfl_xor(s, off, 64);
    int lane = threadIdx.x & 63, wid = threadIdx.x >> 6;
    if (lane == 0) red[wid] = s;
    __syncthreads();
    if (threadIdx.x == 0) part[blockIdx.x] = red[0] + red[1] + red[2] + red[3];
}

// Stage 2: single-wave exclusive scan of <=64 partials; also bbase[nb] = E.
__global__ void scan_h_mid(int* __restrict__ part, int* __restrict__ bbaseN,
                           int nParts, int nE) {
    int tid = threadIdx.x;
    int v = (tid < nParts) ? part[tid] : 0;
    int x = v;
    #pragma unroll
    for (int off = 1; off < 64; off <<= 1) { int y = __shfl_up(x, off, 64); if (tid >= off) x += y; }
    if (tid < nParts) part[tid] = x - v;
    if (tid == 0) bbaseN[0] = nE;
}

// Stage 3: apply offsets, write exclusive positions back to H, emit bbase[b].
__global__ __launch_bounds__(256) void scan_h_final(
        int* __restrict__ H, const int* __restrict__ part,
        int* __restrict__ bbase, int total) {
    __shared__ int wtot[4];
    int tid = threadIdx.x, lane = tid & 63, wid = tid >> 6;
    int base = blockIdx.x * SCHUNK + tid * 16;
    int v[16]; int t = 0;
    #pragma unroll
    for (int k = 0; k < 16; ++k) { int i = base + k; v[k] = (i < total) ? H[i] : 0; t += v[k]; }
    int x = t;
    #pragma unroll
    for (int off = 1; off < 64; off <<= 1) { int y = __shfl_up(x, off, 64); if (lane >= off) x += y; }
    if (lane == 63) wtot[wid] = x;
    __syncthreads();
    int woff = 0;
    for (int w = 0; w < wid; ++w) woff += wtot[w];
    int run = part[blockIdx.x] + woff + (x - t);
    #pragma unroll
    for (int k = 0; k < 16; ++k) {
        int i = base + k;
        if (i < total) {
            H[i] = run;
            if ((i & (NBLK - 1)) == 0) bbase[i >> NBLK_LOG] = run;
            run += v[k];
        }
    }
}

// Re-read the same edge range; LDS cursors seeded from scanned H give each
// block a private, mostly-sequential write window per bucket. No global atomics.
__global__ __launch_bounds__(256) void fill2(
        const void* __restrict__ eidx, const int* __restrict__ flagp,
        const int* __restrict__ H, unsigned long long* __restrict__ pairs,
        int nE, int nb, int epb) {
    __shared__ int cur[MAXB];
    const bool idx64 = (*flagp != 0);
    const int* __restrict__ ei32 = (const int*)eidx;
    const long long* __restrict__ ei64 = (const long long*)eidx;
    for (int i = threadIdx.x; i < nb; i += 256)
        cur[i] = H[(i << NBLK_LOG) + blockIdx.x];
    __syncthreads();
    const int e0 = blockIdx.x * epb;
    const int e1 = min(e0 + epb, nE);
    for (int e = e0 + threadIdx.x; e < e1; e += 256) {
        int s, d;
        if (idx64) { s = (int)ei64[e]; d = (int)ei64[e + nE]; }
        else       { s = ei32[e];      d = ei32[e + nE]; }
        int pos = atomicAdd(&cur[d >> BSHIFT], 1);
        pairs[pos] = (unsigned long long)(unsigned)s
                   | ((unsigned long long)(unsigned)(d & (BN - 1)) << 32);
    }
}

// One block per bucket: LDS count + block scan over BN local nodes, emit
// rowStart (coalesced) and dst-sorted srcs (within the bucket's region).
__global__ __launch_bounds__(512) void bucket_to_csr(
        const unsigned long long* __restrict__ pairs,
        const int* __restrict__ bbase,
        int* __restrict__ rowStart, int* __restrict__ srcs,
        int N, int nb, int nE) {
    __shared__ int lcnt[BN];
    __shared__ int lcur[BN];
    __shared__ int wtot[8];
    const int b = blockIdx.x;
    const int base = bbase[b];
    const int cnt  = bbase[b + 1] - base;
    const int tid = threadIdx.x, lane = tid & 63, wid = tid >> 6;
    lcnt[tid] = 0;
    __syncthreads();
    for (int i = tid; i < cnt; i += 512)
        atomicAdd(&lcnt[(int)(pairs[base + i] >> 32)], 1);
    __syncthreads();
    int v = lcnt[tid];
    int x = v;
    #pragma unroll
    for (int off = 1; off < 64; off <<= 1) { int y = __shfl_up(x, off, 64); if (lane >= off) x += y; }
    if (lane == 63) wtot[wid] = x;
    __syncthreads();
    if (tid == 0) {
        int r = 0;
        for (int w = 0; w < 8; ++w) { int t = wtot[w]; wtot[w] = r; r += t; }
    }
    __syncthreads();
    int excl = wtot[wid] + (x - v);
    lcur[tid] = excl;
    int node = b * BN + tid;
    if (node < N) rowStart[node] = base + excl;
    if (b == nb - 1 && tid == 0) rowStart[N] = nE;
    __syncthreads();
    for (int i = tid; i < cnt; i += 512) {
        unsigned long long p = pairs[base + i];
        int pos = atomicAdd(&lcur[(int)(p >> 32)], 1);
        srcs[base + pos] = (int)(unsigned)p;
    }
}

// ---------------- layer stage 1: gather + mean (latency-optimized) ---------
__global__ __launch_bounds__(256) void gather_mean(
        const float* __restrict__ x,
        const int* __restrict__ rowStart,
        const int* __restrict__ srcs,
        float* __restrict__ agg,
        int nNodes) {
    const int tid = threadIdx.x;
    const int gl = tid & 15;          // lane within group (feature chunk)
    const int grp = tid >> 4;         // group within block (node)
    const int node = blockIdx.x * 16 + grp;
    if (node >= nNodes) return;
    const int r0 = rowStart[node], r1 = rowStart[node + 1];
    float ax = 0.f, ay = 0.f, az = 0.f, aw = 0.f;
    int j = r0;
    for (; j + 4 <= r1; j += 4) {
        int s0 = srcs[j], s1 = srcs[j + 1], s2 = srcs[j + 2], s3 = srcs[j + 3];
        float4 v0 = *(const float4*)&x[(size_t)s0 * D + gl * 4];
        float4 v1 = *(const float4*)&x[(size_t)s1 * D + gl * 4];
        float4 v2 = *(const float4*)&x[(size_t)s2 * D + gl * 4];
        float4 v3 = *(const float4*)&x[(size_t)s3 * D + gl * 4];
        ax += v0.x + v2.x; ay += v0.y + v2.y; az += v0.z + v2.z; aw += v0.w + v2.w;
        ax += v1.x + v3.x; ay += v1.y + v3.y; az += v1.z + v3.z; aw += v1.w + v3.w;
    }
    if (j + 2 <= r1) {
        int s0 = srcs[j], s1 = srcs[j + 1];
        float4 v0 = *(const float4*)&x[(size_t)s0 * D + gl * 4];
        float4 v1 = *(const float4*)&x[(size_t)s1 * D + gl * 4];
        ax += v0.x + v1.x; ay += v0.y + v1.y; az += v0.z + v1.z; aw += v0.w + v1.w;
        j += 2;
    }
    if (j < r1) {
        int s = srcs[j];
        float4 v = *(const float4*)&x[(size_t)s * D + gl * 4];
        ax += v.x; ay += v.y; az += v.z; aw += v.w;
    }
    const float inv = 1.0f / fmaxf((float)(r1 - r0), 1.0f);
    float4 o; o.x = ax * inv; o.y = ay * inv; o.z = az * inv; o.w = aw * inv;
    *(float4*)&agg[(size_t)node * D + gl * 4] = o;
}

// ---------------- layer stage 2: register-blocked f32 GEMM update ----------
__global__ __launch_bounds__(256) void gemm_update(
        const float* __restrict__ agg,
        const float* __restrict__ xin,
        const float* __restrict__ wl,
        const float* __restrict__ bl,
        const float* __restrict__ wr,
        float* __restrict__ xout,
        int nNodes, int mode) {
    __shared__ float sA[D][GN + 4];
    __shared__ float sW[D][D + 4];
    const int tid = threadIdx.x;
    const int fx = tid & 15, nx = tid >> 4;
    const int f0 = fx * 4, n0 = nx * 8;
    const int nb = blockIdx.x * GN;

    float c[8][4];
    #pragma unroll
    for (int i = 0; i < 8; ++i)
        #pragma unroll
        for (int j = 0; j < 4; ++j) c[i][j] = 0.f;

    #pragma unroll
    for (int phase = 0; phase < 2; ++phase) {
        const float* __restrict__ gA = phase ? xin : agg;
        const float* __restrict__ gW = phase ? wr : wl;
        if (phase) __syncthreads();
        for (int i = tid; i < GN * D; i += 256) {
            int n = i >> 6, k = i & 63;
            int gn = nb + n;
            sA[k][n] = (gn < nNodes) ? gA[(size_t)gn * D + k] : 0.f;
        }
        for (int i = tid; i < D * D; i += 256) {
            int f = i >> 6, k = i & 63;
            sW[k][f] = gW[i];
        }
        __syncthreads();
        #pragma unroll 8
        for (int k = 0; k < D; ++k) {
            float4 a0 = *(const float4*)&sA[k][n0];
            float4 a1 = *(const float4*)&sA[k][n0 + 4];
            float4 w  = *(const float4*)&sW[k][f0];
            float av[8] = {a0.x, a0.y, a0.z, a0.w, a1.x, a1.y, a1.z, a1.w};
            float wv[4] = {w.x, w.y, w.z, w.w};
            #pragma unroll
            for (int i = 0; i < 8; ++i)
                #pragma unroll
                for (int j = 0; j < 4; ++j)
                    c[i][j] = fmaf(av[i], wv[j], c[i][j]);
        }
    }

    float4 bv = *(const float4*)&bl[f0];
    float blv[4] = {bv.x, bv.y, bv.z, bv.w};
    #pragma unroll
    for (int i = 0; i < 8; ++i) {
        int gn = nb + n0 + i;
        float o[4];
        #pragma unroll
        for (int j = 0; j < 4; ++j) o[j] = c[i][j] + blv[j];
        if (mode == 0) {
            #pragma unroll
            for (int j = 0; j < 4; ++j) o[j] = fmaxf(o[j], 0.f);
        } else {
            float ss = o[0]*o[0] + o[1]*o[1] + o[2]*o[2] + o[3]*o[3];
            #pragma unroll
            for (int off = 8; off >= 1; off >>= 1) ss += __shfl_xor(ss, off, 16);
            float inv = 1.0f / fmaxf(sqrtf(ss), 1e-12f);
            #pragma unroll
            for (int j = 0; j < 4; ++j) o[j] *= inv;
        }
        if (gn < nNodes) {
            float4 ov; ov.x = o[0]; ov.y = o[1]; ov.z = o[2]; ov.w = o[3];
            *(float4*)&xout[(size_t)gn * D + f0] = ov;
        }
    }
}

// ---------------- fallback: atomic scatter path (round-1, known-correct) ----

__global__ __launch_bounds__(256) void sage_scatter(
        const float* __restrict__ x,
        const void* __restrict__ eidx,
        const int* __restrict__ flagp,
        float* __restrict__ agg,
        float* __restrict__ deg,
        int nE, int doDeg) {
    const bool idx64 = (*flagp != 0);
    const int lane = threadIdx.x & 63;
    int wave = (int)((blockIdx.x * blockDim.x + threadIdx.x) >> 6);
    const int waveStride = (int)((gridDim.x * blockDim.x) >> 6);
    const int* __restrict__ ei32 = (const int*)eidx;
    const long long* __restrict__ ei64 = (const long long*)eidx;
    for (int e = wave; e < nE; e += waveStride) {
        int s, d;
        if (idx64) { s = (int)ei64[e]; d = (int)ei64[e + nE]; }
        else       { s = ei32[e];      d = ei32[e + nE]; }
        atomicAdd(&agg[(size_t)d * D + lane], x[(size_t)s * D + lane]);
        if (doDeg && lane == 0) atomicAdd(&deg[d], 1.0f);
    }
}

__global__ __launch_bounds__(256) void sage_update(
        const float* __restrict__ xin,
        const float* __restrict__ agg,
        const float* __restrict__ deg,
        const float* __restrict__ wl,
        const float* __restrict__ bl,
        const float* __restrict__ wr,
        float* __restrict__ xout,
        int nNodes, int mode) {
    __shared__ float wlT[D * D];
    __shared__ float wrT[D * D];
    __shared__ float rowA[4][D];
    __shared__ float rowX[4][D];
    for (int i = threadIdx.x; i < D * D; i += blockDim.x) {
        int f = i >> 6, k = i & 63;
        wlT[k * D + f] = wl[i];
        wrT[k * D + f] = wr[i];
    }
    __syncthreads();
    const int lane = threadIdx.x & 63;
    const int wid = threadIdx.x >> 6;
    const float blv = bl[lane];
    for (int node = blockIdx.x * 4 + wid; node < nNodes; node += gridDim.x * 4) {
        float dg = fmaxf(deg[node], 1.0f);
        float a  = agg[(size_t)node * D + lane] / dg;
        float xv = xin[(size_t)node * D + lane];
        rowA[wid][lane] = a;
        rowX[wid][lane] = xv;
        float acc = blv;
        #pragma unroll
        for (int k = 0; k < D; ++k) {
            acc = fmaf(rowA[wid][k], wlT[k * D + lane], acc);
            acc = fmaf(rowX[wid][k], wrT[k * D + lane], acc);
        }
        if (mode == 0) {
            xout[(size_t)node * D + lane] = fmaxf(acc, 0.0f);
        } else {
            float ss = acc * acc;
            #pragma unroll
            for (int off = 32; off >= 1; off >>= 1) ss += __shfl_xor(ss, off, 64);
            xout[(size_t)node * D + lane] = acc / fmaxf(sqrtf(ss), 1e-12f);
        }
    }
}

extern "C" void kernel_launch(void* const* d_in, const int* in_sizes, int n_in,
                              void* d_out, int out_size, void* d_ws, size_t ws_size,
                              hipStream_t stream) {
    const float* x   = (const float*)d_in[0];
    const float* wl0 = (const float*)d_in[1];
    const float* bl0 = (const float*)d_in[2];
    const float* wr0 = (const float*)d_in[3];
    const float* wl1 = (const float*)d_in[4];
    const float* bl1 = (const float*)d_in[5];
    const float* wr1 = (const float*)d_in[6];
    const void*  ei  = d_in[7];
    float* out = (float*)d_out;

    const int N = in_sizes[0] / D;
    const int E = in_sizes[7] / 2;
    const int NB = (N + BN - 1) / BN;        // 196 for N=100000
    const int EPB = (E + NBLK - 1) / NBLK;   // edges per partition block
    const int TOTAL = NB << NBLK_LOG;        // H entries
    const int NPARTS = (TOTAL + SCHUNK - 1) / SCHUNK;   // <=16 for N<=131072

    char* ws = (char*)d_ws;
    size_t off = 0;
    auto alloc = [&](size_t bytes) { void* p = ws + off; off = (off + bytes + 255) & ~(size_t)255; return p; };

    size_t shared_bytes = (size_t)E * 8;
    if ((size_t)N * D * 4 > shared_bytes) shared_bytes = (size_t)N * D * 4;
    size_t need = 0;
    {
        size_t o = 0;
        auto sim = [&](size_t b) { o = (o + b + 255) & ~(size_t)255; };
        sim(4); sim(((size_t)MAXB << NBLK_LOG) * 4); sim(64 * 4); sim(((size_t)MAXB + 1) * 4);
        sim(((size_t)N + 1) * 4); sim((size_t)E * 4); sim((size_t)N * D * 4);
        sim(shared_bytes);
        need = o;
    }

    if (ws_size >= need && NB <= MAXB && NPARTS <= 64) {
        int* flag     = (int*)alloc(4);
        int* H        = (int*)alloc(((size_t)MAXB << NBLK_LOG) * 4);
        int* part     = (int*)alloc(64 * 4);
        int* bbase    = (int*)alloc(((size_t)MAXB + 1) * 4);
        int* rowStart = (int*)alloc(((size_t)N + 1) * 4);
        int* srcs     = (int*)alloc((size_t)E * 4);
        float* x1     = (float*)alloc((size_t)N * D * 4);
        void* shared  = alloc(shared_bytes);
        unsigned long long* pairs = (unsigned long long*)shared;
        float* agg    = (float*)shared;

        detect_idx64<<<1, 64, 0, stream>>>((const int*)ei, flag);
        hist2d<<<NBLK, 256, 0, stream>>>(ei, flag, H, E, NB, EPB);
        scan_h_partial<<<NPARTS, 256, 0, stream>>>(H, part, TOTAL);
        scan_h_mid<<<1, 64, 0, stream>>>(part, &bbase[NB], NPARTS, E);
        scan_h_final<<<NPARTS, 256, 0, stream>>>(H, part, bbase, TOTAL);
        fill2<<<NBLK, 256, 0, stream>>>(ei, flag, H, pairs, E, NB, EPB);
        bucket_to_csr<<<NB, 512, 0, stream>>>(pairs, bbase, rowStart, srcs, N, NB, E);

        const int gGather = (N + 15) / 16;
        const int gGemm   = (N + GN - 1) / GN;
        gather_mean<<<gGather, 256, 0, stream>>>(x, rowStart, srcs, agg, N);
        gemm_update<<<gGemm, 256, 0, stream>>>(agg, x, wl0, bl0, wr0, x1, N, 0);
        gather_mean<<<gGather, 256, 0, stream>>>(x1, rowStart, srcs, agg, N);
        gemm_update<<<gGemm, 256, 0, stream>>>(agg, x1, wl1, bl1, wr1, out, N, 1);
    } else {
        // fallback: round-1 scatter path (~26 MB ws)
        int*   flag = (int*)alloc(4);
        float* deg  = (float*)alloc((size_t)N * 4);
        float* agg  = (float*)alloc((size_t)N * D * 4);
        float* x1   = out;  // safe: sage_update reads only its own row of xin

        detect_idx64<<<1, 64, 0, stream>>>((const int*)ei, flag);
        hipMemsetAsync(deg, 0, ((size_t)N + (size_t)N * D) * 4, stream);
        sage_scatter<<<4096, 256, 0, stream>>>(x, ei, flag, agg, deg, E, 1);
        sage_update<<<2048, 256, 0, stream>>>(x, agg, deg, wl0, bl0, wr0, x1, N, 0);
        hipMemsetAsync(agg, 0, (size_t)N * D * 4, stream);
        sage_scatter<<<4096, 256, 0, stream>>>(x1, ei, flag, agg, deg, E, 0);
        sage_update<<<2048, 256, 0, stream>>>(x1, agg, deg, wl1, bl1, wr1, out, N, 1);
    }
}

// Round 8
// 253.876 us; speedup vs baseline: 2.6335x; 1.2044x over previous
//
#include <hip/hip_runtime.h>
#include <math.h>

#define D 64
#define GN 128        // nodes per gemm_update (VALU fallback) block
#define BSHIFT 9      // bucket = dst >> 9 (512 nodes per bucket)
#define BN 512        // nodes per bucket
#define MAXB 256      // max buckets (N <= 131072)
#define NBLK 256      // partition blocks for hist2d/fill2
#define NBLK_LOG 8
#define SCHUNK 4096   // H entries per scan block (256 thr x 16)

typedef short bf16x8v __attribute__((ext_vector_type(8)));
typedef float f32x4v __attribute__((ext_vector_type(4)));

__device__ __forceinline__ unsigned short f2bf(float f) {   // round-to-nearest-even
    unsigned u = __float_as_uint(f);
    return (unsigned short)((u + 0x7FFFu + ((u >> 16) & 1u)) >> 16);
}
__device__ __forceinline__ float bf2f(unsigned short b) {
    return __uint_as_float(((unsigned)b) << 16);
}

// Detect whether edge_index is int64 (odd int32 words are zero high-halves)
// or int32 (odd words are random node ids).
__global__ void detect_idx64(const int* __restrict__ ei, int* __restrict__ flag) {
    int v = ei[2 * threadIdx.x + 1];
    unsigned long long b = __ballot(v != 0);
    if (threadIdx.x == 0) flag[0] = (b == 0ULL) ? 1 : 0;
}

// Self-test of the assumed 16x16x32 bf16 MFMA fragment layout (exact integer
// arithmetic, transpose-detecting asymmetric inputs). ok=1 iff HW matches.
__global__ void mfma_probe(int* __restrict__ ok) {
    const int l = threadIdx.x;
    const int col = l & 15, grp = l >> 4;
    bf16x8v a, b;
    #pragma unroll
    for (int j = 0; j < 8; ++j) {
        int k = grp * 8 + j;
        a[j] = (short)f2bf((float)(((col * 3 + k) % 7) - 3));      // A[row=col][k]
        b[j] = (short)f2bf((float)(((k * 5 + col * 2) % 9) - 4));  // B[k][n=col]
    }
    f32x4v c = {0.f, 0.f, 0.f, 0.f};
    c = __builtin_amdgcn_mfma_f32_16x16x32_bf16(a, b, c, 0, 0, 0);
    bool good = true;
    #pragma unroll
    for (int r = 0; r < 4; ++r) {
        int row = grp * 4 + r;
        float ref = 0.f;
        for (int k = 0; k < 32; ++k)
            ref += (float)(((row * 3 + k) % 7) - 3) * (float)(((k * 5 + col * 2) % 9) - 4);
        if (c[r] != ref) good = false;
    }
    unsigned long long m = __ballot(good);
    if (l == 0) ok[0] = (m == ~0ULL) ? 1 : 0;
}

// Split the 4 weight matrices (wl0, wr0, wl1, wr1; each 64x64 f32 row-major)
// into bf16 hi/lo arrays with identical layout.
__global__ __launch_bounds__(256) void conv_w4(
        const float* __restrict__ w0, const float* __restrict__ w1,
        const float* __restrict__ w2, const float* __restrict__ w3,
        unsigned short* __restrict__ hi, unsigned short* __restrict__ lo) {
    int i = blockIdx.x * 256 + threadIdx.x;            // 0..16383
    const float* ws_[4] = {w0, w1, w2, w3};
    float f = ws_[i >> 12][i & 4095];
    unsigned short h = f2bf(f);
    hi[i] = h;
    lo[i] = f2bf(f - bf2f(h));
}

// ---------------- deterministic counting-sort CSR build ----------------

__global__ __launch_bounds__(256) void hist2d(
        const void* __restrict__ eidx, const int* __restrict__ flagp,
        int* __restrict__ H, int nE, int nb, int epb) {
    __shared__ int h[MAXB];
    const bool idx64 = (*flagp != 0);
    const int* __restrict__ ei32 = (const int*)eidx;
    const long long* __restrict__ ei64 = (const long long*)eidx;
    for (int i = threadIdx.x; i < nb; i += 256) h[i] = 0;
    __syncthreads();
    const int e0 = blockIdx.x * epb;
    const int e1 = min(e0 + epb, nE);
    for (int e = e0 + threadIdx.x; e < e1; e += 256) {
        int d = idx64 ? (int)ei64[e + nE] : ei32[e + nE];
        atomicAdd(&h[d >> BSHIFT], 1);
    }
    __syncthreads();
    for (int i = threadIdx.x; i < nb; i += 256)
        H[(i << NBLK_LOG) + blockIdx.x] = h[i];
}

__global__ __launch_bounds__(256) void scan_h_partial(
        const int* __restrict__ H, int* __restrict__ part, int total) {
    __shared__ int red[4];
    int base = blockIdx.x * SCHUNK + threadIdx.x * 16;
    int s = 0;
    #pragma unroll
    for (int k = 0; k < 16; ++k) { int i = base + k; if (i < total) s += H[i]; }
    #pragma unroll
    for (int off = 32; off >= 1; off >>= 1) s += __shfl_xor(s, off, 64);
    int lane = threadIdx.x & 63, wid = threadIdx.x >> 6;
    if (lane == 0) red[wid] = s;
    __syncthreads();
    if (threadIdx.x == 0) part[blockIdx.x] = red[0] + red[1] + red[2] + red[3];
}

__global__ void scan_h_mid(int* __restrict__ part, int* __restrict__ bbaseN,
                           int nParts, int nE) {
    int tid = threadIdx.x;
    int v = (tid < nParts) ? part[tid] : 0;
    int x = v;
    #pragma unroll
    for (int off = 1; off < 64; off <<= 1) { int y = __shfl_up(x, off, 64); if (tid >= off) x += y; }
    if (tid < nParts) part[tid] = x - v;
    if (tid == 0) bbaseN[0] = nE;
}

__global__ __launch_bounds__(256) void scan_h_final(
        int* __restrict__ H, const int* __restrict__ part,
        int* __restrict__ bbase, int total) {
    __shared__ int wtot[4];
    int tid = threadIdx.x, lane = tid & 63, wid = tid >> 6;
    int base = blockIdx.x * SCHUNK + tid * 16;
    int v[16]; int t = 0;
    #pragma unroll
    for (int k = 0; k < 16; ++k) { int i = base + k; v[k] = (i < total) ? H[i] : 0; t += v[k]; }
    int x = t;
    #pragma unroll
    for (int off = 1; off < 64; off <<= 1) { int y = __shfl_up(x, off, 64); if (lane >= off) x += y; }
    if (lane == 63) wtot[wid] = x;
    __syncthreads();
    int woff = 0;
    for (int w = 0; w < wid; ++w) woff += wtot[w];
    int run = part[blockIdx.x] + woff + (x - t);
    #pragma unroll
    for (int k = 0; k < 16; ++k) {
        int i = base + k;
        if (i < total) {
            H[i] = run;
            if ((i & (NBLK - 1)) == 0) bbase[i >> NBLK_LOG] = run;
            run += v[k];
        }
    }
}

__global__ __launch_bounds__(256) void fill2(
        const void* __restrict__ eidx, const int* __restrict__ flagp,
        const int* __restrict__ H, unsigned long long* __restrict__ pairs,
        int nE, int nb, int epb) {
    __shared__ int cur[MAXB];
    const bool idx64 = (*flagp != 0);
    const int* __restrict__ ei32 = (const int*)eidx;
    const long long* __restrict__ ei64 = (const long long*)eidx;
    for (int i = threadIdx.x; i < nb; i += 256)
        cur[i] = H[(i << NBLK_LOG) + blockIdx.x];
    __syncthreads();
    const int e0 = blockIdx.x * epb;
    const int e1 = min(e0 + epb, nE);
    for (int e = e0 + threadIdx.x; e < e1; e += 256) {
        int s, d;
        if (idx64) { s = (int)ei64[e]; d = (int)ei64[e + nE]; }
        else       { s = ei32[e];      d = ei32[e + nE]; }
        int pos = atomicAdd(&cur[d >> BSHIFT], 1);
        pairs[pos] = (unsigned long long)(unsigned)s
                   | ((unsigned long long)(unsigned)(d & (BN - 1)) << 32);
    }
}

__global__ __launch_bounds__(512) void bucket_to_csr(
        const unsigned long long* __restrict__ pairs,
        const int* __restrict__ bbase,
        int* __restrict__ rowStart, int* __restrict__ srcs,
        int N, int nb, int nE) {
    __shared__ int lcnt[BN];
    __shared__ int lcur[BN];
    __shared__ int wtot[8];
    const int b = blockIdx.x;
    const int base = bbase[b];
    const int cnt  = bbase[b + 1] - base;
    const int tid = threadIdx.x, lane = tid & 63, wid = tid >> 6;
    lcnt[tid] = 0;
    __syncthreads();
    for (int i = tid; i < cnt; i += 512)
        atomicAdd(&lcnt[(int)(pairs[base + i] >> 32)], 1);
    __syncthreads();
    int v = lcnt[tid];
    int x = v;
    #pragma unroll
    for (int off = 1; off < 64; off <<= 1) { int y = __shfl_up(x, off, 64); if (lane >= off) x += y; }
    if (lane == 63) wtot[wid] = x;
    __syncthreads();
    if (tid == 0) {
        int r = 0;
        for (int w = 0; w < 8; ++w) { int t = wtot[w]; wtot[w] = r; r += t; }
    }
    __syncthreads();
    int excl = wtot[wid] + (x - v);
    lcur[tid] = excl;
    int node = b * BN + tid;
    if (node < N) rowStart[node] = base + excl;
    if (b == nb - 1 && tid == 0) rowStart[N] = nE;
    __syncthreads();
    for (int i = tid; i < cnt; i += 512) {
        unsigned long long p = pairs[base + i];
        int pos = atomicAdd(&lcur[(int)(p >> 32)], 1);
        srcs[base + pos] = (int)(unsigned)p;
    }
}

// ---------------- layer stage 1: gather + mean (latency-optimized) ---------
__global__ __launch_bounds__(256) void gather_mean(
        const float* __restrict__ x,
        const int* __restrict__ rowStart,
        const int* __restrict__ srcs,
        float* __restrict__ agg,
        int nNodes) {
    const int tid = threadIdx.x;
    const int gl = tid & 15;
    const int grp = tid >> 4;
    const int node = blockIdx.x * 16 + grp;
    if (node >= nNodes) return;
    const int r0 = rowStart[node], r1 = rowStart[node + 1];
    float ax = 0.f, ay = 0.f, az = 0.f, aw = 0.f;
    int j = r0;
    for (; j + 4 <= r1; j += 4) {
        int s0 = srcs[j], s1 = srcs[j + 1], s2 = srcs[j + 2], s3 = srcs[j + 3];
        float4 v0 = *(const float4*)&x[(size_t)s0 * D + gl * 4];
        float4 v1 = *(const float4*)&x[(size_t)s1 * D + gl * 4];
        float4 v2 = *(const float4*)&x[(size_t)s2 * D + gl * 4];
        float4 v3 = *(const float4*)&x[(size_t)s3 * D + gl * 4];
        ax += v0.x + v2.x; ay += v0.y + v2.y; az += v0.z + v2.z; aw += v0.w + v2.w;
        ax += v1.x + v3.x; ay += v1.y + v3.y; az += v1.z + v3.z; aw += v1.w + v3.w;
    }
    if (j + 2 <= r1) {
        int s0 = srcs[j], s1 = srcs[j + 1];
        float4 v0 = *(const float4*)&x[(size_t)s0 * D + gl * 4];
        float4 v1 = *(const float4*)&x[(size_t)s1 * D + gl * 4];
        ax += v0.x + v1.x; ay += v0.y + v1.y; az += v0.z + v1.z; aw += v0.w + v1.w;
        j += 2;
    }
    if (j < r1) {
        int s = srcs[j];
        float4 v = *(const float4*)&x[(size_t)s * D + gl * 4];
        ax += v.x; ay += v.y; az += v.z; aw += v.w;
    }
    const float inv = 1.0f / fmaxf((float)(r1 - r0), 1.0f);
    float4 o; o.x = ax * inv; o.y = ay * inv; o.z = az * inv; o.w = aw * inv;
    *(float4*)&agg[(size_t)node * D + gl * 4] = o;
}

// ---------------- layer stage 2: split-bf16 MFMA GEMM update ----------------
// out = agg @ wl^T + bl + xin @ wr^T with 3-term bf16 hi/lo MFMA (err ~2^-17).
// Per wave: 16 nodes x 64 features; no LDS, no barriers. wHi/wLo = [wl|wr].
__global__ __launch_bounds__(256) void gemm_mfma(
        const float* __restrict__ agg,
        const float* __restrict__ xin,
        const unsigned short* __restrict__ wHi,
        const unsigned short* __restrict__ wLo,
        const float* __restrict__ bl,
        float* __restrict__ xout,
        int nNodes, int mode, const int* __restrict__ okp) {
    if (!*okp) return;
    const int l = threadIdx.x & 63;
    const int wv = threadIdx.x >> 6;
    const int col = l & 15, grp = l >> 4;
    const int base = blockIdx.x * 64 + wv * 16;
    if (base >= nNodes) return;

    const int anode = min(base + col, nNodes - 1);
    const float* pa = agg + (size_t)anode * D;
    const float* px = xin + (size_t)anode * D;
    bf16x8v aH[2][2], aL[2][2];
    #pragma unroll
    for (int s = 0; s < 2; ++s) {
        const float* p = s ? px : pa;
        #pragma unroll
        for (int h = 0; h < 2; ++h) {
            const int k0 = h * 32 + grp * 8;
            float4 u0 = *(const float4*)(p + k0);
            float4 u1 = *(const float4*)(p + k0 + 4);
            float v[8] = {u0.x, u0.y, u0.z, u0.w, u1.x, u1.y, u1.z, u1.w};
            #pragma unroll
            for (int j = 0; j < 8; ++j) {
                unsigned short hb = f2bf(v[j]);
                aH[s][h][j] = (short)hb;
                aL[s][h][j] = (short)f2bf(v[j] - bf2f(hb));
            }
        }
    }

    f32x4v acc[4];
    #pragma unroll
    for (int t = 0; t < 4; ++t) {
        acc[t] = (f32x4v){0.f, 0.f, 0.f, 0.f};
        #pragma unroll
        for (int s = 0; s < 2; ++s) {
            const unsigned short* wh = wHi + s * 4096 + (size_t)(t * 16 + col) * D;
            const unsigned short* wo = wLo + s * 4096 + (size_t)(t * 16 + col) * D;
            #pragma unroll
            for (int h = 0; h < 2; ++h) {
                const int k0 = h * 32 + grp * 8;
                bf16x8v bh = *(const bf16x8v*)(wh + k0);
                bf16x8v bo = *(const bf16x8v*)(wo + k0);
                acc[t] = __builtin_amdgcn_mfma_f32_16x16x32_bf16(aH[s][h], bh, acc[t], 0, 0, 0);
                acc[t] = __builtin_amdgcn_mfma_f32_16x16x32_bf16(aL[s][h], bh, acc[t], 0, 0, 0);
                acc[t] = __builtin_amdgcn_mfma_f32_16x16x32_bf16(aH[s][h], bo, acc[t], 0, 0, 0);
            }
        }
    }

    #pragma unroll
    for (int t = 0; t < 4; ++t) {
        float b = bl[t * 16 + col];
        #pragma unroll
        for (int r = 0; r < 4; ++r) acc[t][r] += b;
    }

    if (mode == 0) {
        #pragma unroll
        for (int t = 0; t < 4; ++t)
            #pragma unroll
            for (int r = 0; r < 4; ++r) {
                int n = base + grp * 4 + r;
                if (n < nNodes)
                    xout[(size_t)n * D + t * 16 + col] = fmaxf(acc[t][r], 0.f);
            }
    } else {
        float ss[4] = {0.f, 0.f, 0.f, 0.f};
        #pragma unroll
        for (int t = 0; t < 4; ++t)
            #pragma unroll
            for (int r = 0; r < 4; ++r) ss[r] += acc[t][r] * acc[t][r];
        #pragma unroll
        for (int r = 0; r < 4; ++r) {
            #pragma unroll
            for (int off = 1; off < 16; off <<= 1) ss[r] += __shfl_xor(ss[r], off, 64);
        }
        float inv[4];
        #pragma unroll
        for (int r = 0; r < 4; ++r) inv[r] = 1.0f / fmaxf(sqrtf(ss[r]), 1e-12f);
        #pragma unroll
        for (int t = 0; t < 4; ++t)
            #pragma unroll
            for (int r = 0; r < 4; ++r) {
                int n = base + grp * 4 + r;
                if (n < nNodes)
                    xout[(size_t)n * D + t * 16 + col] = acc[t][r] * inv[r];
            }
    }
}

// ---------------- VALU GEMM (runs only if mfma_probe failed) ---------------
__global__ __launch_bounds__(256) void gemm_update(
        const float* __restrict__ agg,
        const float* __restrict__ xin,
        const float* __restrict__ wl,
        const float* __restrict__ bl,
        const float* __restrict__ wr,
        float* __restrict__ xout,
        int nNodes, int mode, const int* __restrict__ okp) {
    if (*okp) return;   // uniform early-exit before any barrier
    __shared__ float sA[D][GN + 4];
    __shared__ float sW[D][D + 4];
    const int tid = threadIdx.x;
    const int fx = tid & 15, nx = tid >> 4;
    const int f0 = fx * 4, n0 = nx * 8;
    const int nb = blockIdx.x * GN;

    float c[8][4];
    #pragma unroll
    for (int i = 0; i < 8; ++i)
        #pragma unroll
        for (int j = 0; j < 4; ++j) c[i][j] = 0.f;

    #pragma unroll
    for (int phase = 0; phase < 2; ++phase) {
        const float* __restrict__ gA = phase ? xin : agg;
        const float* __restrict__ gW = phase ? wr : wl;
        if (phase) __syncthreads();
        for (int i = tid; i < GN * D; i += 256) {
            int n = i >> 6, k = i & 63;
            int gn = nb + n;
            sA[k][n] = (gn < nNodes) ? gA[(size_t)gn * D + k] : 0.f;
        }
        for (int i = tid; i < D * D; i += 256) {
            int f = i >> 6, k = i & 63;
            sW[k][f] = gW[i];
        }
        __syncthreads();
        #pragma unroll 8
        for (int k = 0; k < D; ++k) {
            float4 a0 = *(const float4*)&sA[k][n0];
            float4 a1 = *(const float4*)&sA[k][n0 + 4];
            float4 w  = *(const float4*)&sW[k][f0];
            float av[8] = {a0.x, a0.y, a0.z, a0.w, a1.x, a1.y, a1.z, a1.w};
            float wv[4] = {w.x, w.y, w.z, w.w};
            #pragma unroll
            for (int i = 0; i < 8; ++i)
                #pragma unroll
                for (int j = 0; j < 4; ++j)
                    c[i][j] = fmaf(av[i], wv[j], c[i][j]);
        }
    }

    float4 bv = *(const float4*)&bl[f0];
    float blv[4] = {bv.x, bv.y, bv.z, bv.w};
    #pragma unroll
    for (int i = 0; i < 8; ++i) {
        int gn = nb + n0 + i;
        float o[4];
        #pragma unroll
        for (int j = 0; j < 4; ++j) o[j] = c[i][j] + blv[j];
        if (mode == 0) {
            #pragma unroll
            for (int j = 0; j < 4; ++j) o[j] = fmaxf(o[j], 0.f);
        } else {
            float ss = o[0]*o[0] + o[1]*o[1] + o[2]*o[2] + o[3]*o[3];
            #pragma unroll
            for (int off = 8; off >= 1; off >>= 1) ss += __shfl_xor(ss, off, 16);
            float inv = 1.0f / fmaxf(sqrtf(ss), 1e-12f);
            #pragma unroll
            for (int j = 0; j < 4; ++j) o[j] *= inv;
        }
        if (gn < nNodes) {
            float4 ov; ov.x = o[0]; ov.y = o[1]; ov.z = o[2]; ov.w = o[3];
            *(float4*)&xout[(size_t)gn * D + f0] = ov;
        }
    }
}

// ---------------- fallback: atomic scatter path (round-1, known-correct) ----

__global__ __launch_bounds__(256) void sage_scatter(
        const float* __restrict__ x,
        const void* __restrict__ eidx,
        const int* __restrict__ flagp,
        float* __restrict__ agg,
        float* __restrict__ deg,
        int nE, int doDeg) {
    const bool idx64 = (*flagp != 0);
    const int lane = threadIdx.x & 63;
    int wave = (int)((blockIdx.x * blockDim.x + threadIdx.x) >> 6);
    const int waveStride = (int)((gridDim.x * blockDim.x) >> 6);
    const int* __restrict__ ei32 = (const int*)eidx;
    const long long* __restrict__ ei64 = (const long long*)eidx;
    for (int e = wave; e < nE; e += waveStride) {
        int s, d;
        if (idx64) { s = (int)ei64[e]; d = (int)ei64[e + nE]; }
        else       { s = ei32[e];      d = ei32[e + nE]; }
        atomicAdd(&agg[(size_t)d * D + lane], x[(size_t)s * D + lane]);
        if (doDeg && lane == 0) atomicAdd(&deg[d], 1.0f);
    }
}

__global__ __launch_bounds__(256) void sage_update(
        const float* __restrict__ xin,
        const float* __restrict__ agg,
        const float* __restrict__ deg,
        const float* __restrict__ wl,
        const float* __restrict__ bl,
        const float* __restrict__ wr,
        float* __restrict__ xout,
        int nNodes, int mode) {
    __shared__ float wlT[D * D];
    __shared__ float wrT[D * D];
    __shared__ float rowA[4][D];
    __shared__ float rowX[4][D];
    for (int i = threadIdx.x; i < D * D; i += blockDim.x) {
        int f = i >> 6, k = i & 63;
        wlT[k * D + f] = wl[i];
        wrT[k * D + f] = wr[i];
    }
    __syncthreads();
    const int lane = threadIdx.x & 63;
    const int wid = threadIdx.x >> 6;
    const float blv = bl[lane];
    for (int node = blockIdx.x * 4 + wid; node < nNodes; node += gridDim.x * 4) {
        float dg = fmaxf(deg[node], 1.0f);
        float a  = agg[(size_t)node * D + lane] / dg;
        float xv = xin[(size_t)node * D + lane];
        rowA[wid][lane] = a;
        rowX[wid][lane] = xv;
        float acc = blv;
        #pragma unroll
        for (int k = 0; k < D; ++k) {
            acc = fmaf(rowA[wid][k], wlT[k * D + lane], acc);
            acc = fmaf(rowX[wid][k], wrT[k * D + lane], acc);
        }
        if (mode == 0) {
            xout[(size_t)node * D + lane] = fmaxf(acc, 0.0f);
        } else {
            float ss = acc * acc;
            #pragma unroll
            for (int off = 32; off >= 1; off >>= 1) ss += __shfl_xor(ss, off, 64);
            xout[(size_t)node * D + lane] = acc / fmaxf(sqrtf(ss), 1e-12f);
        }
    }
}

extern "C" void kernel_launch(void* const* d_in, const int* in_sizes, int n_in,
                              void* d_out, int out_size, void* d_ws, size_t ws_size,
                              hipStream_t stream) {
    const float* x   = (const float*)d_in[0];
    const float* wl0 = (const float*)d_in[1];
    const float* bl0 = (const float*)d_in[2];
    const float* wr0 = (const float*)d_in[3];
    const float* wl1 = (const float*)d_in[4];
    const float* bl1 = (const float*)d_in[5];
    const float* wr1 = (const float*)d_in[6];
    const void*  ei  = d_in[7];
    float* out = (float*)d_out;

    const int N = in_sizes[0] / D;
    const int E = in_sizes[7] / 2;
    const int NB = (N + BN - 1) / BN;
    const int EPB = (E + NBLK - 1) / NBLK;
    const int TOTAL = NB << NBLK_LOG;
    const int NPARTS = (TOTAL + SCHUNK - 1) / SCHUNK;

    char* ws = (char*)d_ws;
    size_t off = 0;
    auto alloc = [&](size_t bytes) { void* p = ws + off; off = (off + bytes + 255) & ~(size_t)255; return p; };

    size_t shared_bytes = (size_t)E * 8;
    if ((size_t)N * D * 4 > shared_bytes) shared_bytes = (size_t)N * D * 4;
    size_t need = 0;
    {
        size_t o = 0;
        auto sim = [&](size_t b) { o = (o + b + 255) & ~(size_t)255; };
        sim(4); sim(4); sim(16384 * 2); sim(16384 * 2);
        sim(((size_t)MAXB << NBLK_LOG) * 4); sim(64 * 4); sim(((size_t)MAXB + 1) * 4);
        sim(((size_t)N + 1) * 4); sim((size_t)E * 4); sim((size_t)N * D * 4);
        sim(shared_bytes);
        need = o;
    }

    if (ws_size >= need && NB <= MAXB && NPARTS <= 64) {
        int* flag     = (int*)alloc(4);
        int* okf      = (int*)alloc(4);
        unsigned short* whi = (unsigned short*)alloc(16384 * 2);
        unsigned short* wlo = (unsigned short*)alloc(16384 * 2);
        int* H        = (int*)alloc(((size_t)MAXB << NBLK_LOG) * 4);
        int* part     = (int*)alloc(64 * 4);
        int* bbase    = (int*)alloc(((size_t)MAXB + 1) * 4);
        int* rowStart = (int*)alloc(((size_t)N + 1) * 4);
        int* srcs     = (int*)alloc((size_t)E * 4);
        float* x1     = (float*)alloc((size_t)N * D * 4);
        void* shared  = alloc(shared_bytes);
        unsigned long long* pairs = (unsigned long long*)shared;
        float* agg    = (float*)shared;

        detect_idx64<<<1, 64, 0, stream>>>((const int*)ei, flag);
        mfma_probe<<<1, 64, 0, stream>>>(okf);
        conv_w4<<<64, 256, 0, stream>>>(wl0, wr0, wl1, wr1, whi, wlo);
        hist2d<<<NBLK, 256, 0, stream>>>(ei, flag, H, E, NB, EPB);
        scan_h_partial<<<NPARTS, 256, 0, stream>>>(H, part, TOTAL);
        scan_h_mid<<<1, 64, 0, stream>>>(part, &bbase[NB], NPARTS, E);
        scan_h_final<<<NPARTS, 256, 0, stream>>>(H, part, bbase, TOTAL);
        fill2<<<NBLK, 256, 0, stream>>>(ei, flag, H, pairs, E, NB, EPB);
        bucket_to_csr<<<NB, 512, 0, stream>>>(pairs, bbase, rowStart, srcs, N, NB, E);

        const int gGather = (N + 15) / 16;
        const int gMfma   = (N + 63) / 64;
        const int gGemm   = (N + GN - 1) / GN;
        gather_mean<<<gGather, 256, 0, stream>>>(x, rowStart, srcs, agg, N);
        gemm_mfma<<<gMfma, 256, 0, stream>>>(agg, x, whi, wlo, bl0, x1, N, 0, okf);
        gemm_update<<<gGemm, 256, 0, stream>>>(agg, x, wl0, bl0, wr0, x1, N, 0, okf);
        gather_mean<<<gGather, 256, 0, stream>>>(x1, rowStart, srcs, agg, N);
        gemm_mfma<<<gMfma, 256, 0, stream>>>(agg, x1, whi + 2 * 4096, wlo + 2 * 4096, bl1, out, N, 1, okf);
        gemm_update<<<gGemm, 256, 0, stream>>>(agg, x1, wl1, bl1, wr1, out, N, 1, okf);
    } else {
        // fallback: round-1 scatter path (~26 MB ws)
        int*   flag = (int*)alloc(4);
        float* deg  = (float*)alloc((size_t)N * 4);
        float* agg  = (float*)alloc((size_t)N * D * 4);
        float* x1   = out;  // safe: sage_update reads only its own row of xin

        detect_idx64<<<1, 64, 0, stream>>>((const int*)ei, flag);
        hipMemsetAsync(deg, 0, ((size_t)N + (size_t)N * D) * 4, stream);
        sage_scatter<<<4096, 256, 0, stream>>>(x, ei, flag, agg, deg, E, 1);
        sage_update<<<2048, 256, 0, stream>>>(x, agg, deg, wl0, bl0, wr0, x1, N, 0);
        hipMemsetAsync(agg, 0, (size_t)N * D * 4, stream);
        sage_scatter<<<4096, 256, 0, stream>>>(x1, ei, flag, agg, deg, E, 0);
        sage_update<<<2048, 256, 0, stream>>>(x1, agg, deg, wl1, bl1, wr1, out, N, 1);
    }
}

// Round 9
// 212.025 us; speedup vs baseline: 3.1533x; 1.1974x over previous
//
#include <hip/hip_runtime.h>
#include <math.h>

#define D 64
#define GN 128        // nodes per gemm_update (VALU fallback) block
#define BSHIFT 9      // bucket = dst >> 9 (512 nodes per bucket)
#define BN 512        // nodes per bucket
#define MAXB 256      // max buckets (N <= 131072)
#define NBLK 256      // partition blocks for hist2d/fill2
#define NBLK_LOG 8
#define SCHUNK 4096   // H entries per scan block (256 thr x 16)

typedef short bf16x8v __attribute__((ext_vector_type(8)));
typedef float f32x4v __attribute__((ext_vector_type(4)));

__device__ __forceinline__ unsigned short f2bf(float f) {   // round-to-nearest-even
    unsigned u = __float_as_uint(f);
    return (unsigned short)((u + 0x7FFFu + ((u >> 16) & 1u)) >> 16);
}
__device__ __forceinline__ float bf2f(unsigned short b) {
    return __uint_as_float(((unsigned)b) << 16);
}

// Detect whether edge_index is int64 (odd int32 words are zero high-halves)
// or int32 (odd words are random node ids).
__global__ void detect_idx64(const int* __restrict__ ei, int* __restrict__ flag) {
    int v = ei[2 * threadIdx.x + 1];
    unsigned long long b = __ballot(v != 0);
    if (threadIdx.x == 0) flag[0] = (b == 0ULL) ? 1 : 0;
}

// Self-test of the assumed 16x16x32 bf16 MFMA fragment layout (exact integer
// arithmetic, transpose-detecting asymmetric inputs). ok=1 iff HW matches.
__global__ void mfma_probe(int* __restrict__ ok) {
    const int l = threadIdx.x;
    const int col = l & 15, grp = l >> 4;
    bf16x8v a, b;
    #pragma unroll
    for (int j = 0; j < 8; ++j) {
        int k = grp * 8 + j;
        a[j] = (short)f2bf((float)(((col * 3 + k) % 7) - 3));      // A[row=col][k]
        b[j] = (short)f2bf((float)(((k * 5 + col * 2) % 9) - 4));  // B[k][n=col]
    }
    f32x4v c = {0.f, 0.f, 0.f, 0.f};
    c = __builtin_amdgcn_mfma_f32_16x16x32_bf16(a, b, c, 0, 0, 0);
    bool good = true;
    #pragma unroll
    for (int r = 0; r < 4; ++r) {
        int row = grp * 4 + r;
        float ref = 0.f;
        for (int k = 0; k < 32; ++k)
            ref += (float)(((row * 3 + k) % 7) - 3) * (float)(((k * 5 + col * 2) % 9) - 4);
        if (c[r] != ref) good = false;
    }
    unsigned long long m = __ballot(good);
    if (l == 0) ok[0] = (m == ~0ULL) ? 1 : 0;
}

// Split the 4 weight matrices (wl0, wr0, wl1, wr1; each 64x64 f32 row-major)
// into bf16 hi/lo arrays with identical layout.
__global__ __launch_bounds__(256) void conv_w4(
        const float* __restrict__ w0, const float* __restrict__ w1,
        const float* __restrict__ w2, const float* __restrict__ w3,
        unsigned short* __restrict__ hi, unsigned short* __restrict__ lo) {
    int i = blockIdx.x * 256 + threadIdx.x;            // 0..16383
    const float* ws_[4] = {w0, w1, w2, w3};
    float f = ws_[i >> 12][i & 4095];
    unsigned short h = f2bf(f);
    hi[i] = h;
    lo[i] = f2bf(f - bf2f(h));
}

// Convert node features f32 -> packed bf16 (uint4 = 8 elems per store).
__global__ __launch_bounds__(256) void conv_xbf(
        const float* __restrict__ x, uint4* __restrict__ xb4, int total8) {
    int i = blockIdx.x * 256 + threadIdx.x;
    int stride = gridDim.x * 256;
    for (; i < total8; i += stride) {
        float4 u0 = *(const float4*)(x + (size_t)i * 8);
        float4 u1 = *(const float4*)(x + (size_t)i * 8 + 4);
        uint4 p;
        p.x = (unsigned)f2bf(u0.x) | ((unsigned)f2bf(u0.y) << 16);
        p.y = (unsigned)f2bf(u0.z) | ((unsigned)f2bf(u0.w) << 16);
        p.z = (unsigned)f2bf(u1.x) | ((unsigned)f2bf(u1.y) << 16);
        p.w = (unsigned)f2bf(u1.z) | ((unsigned)f2bf(u1.w) << 16);
        xb4[i] = p;
    }
}

// ---------------- deterministic counting-sort CSR build ----------------

__global__ __launch_bounds__(256) void hist2d(
        const void* __restrict__ eidx, const int* __restrict__ flagp,
        int* __restrict__ H, int nE, int nb, int epb) {
    __shared__ int h[MAXB];
    const bool idx64 = (*flagp != 0);
    const int* __restrict__ ei32 = (const int*)eidx;
    const long long* __restrict__ ei64 = (const long long*)eidx;
    for (int i = threadIdx.x; i < nb; i += 256) h[i] = 0;
    __syncthreads();
    const int e0 = blockIdx.x * epb;
    const int e1 = min(e0 + epb, nE);
    for (int e = e0 + threadIdx.x; e < e1; e += 256) {
        int d = idx64 ? (int)ei64[e + nE] : ei32[e + nE];
        atomicAdd(&h[d >> BSHIFT], 1);
    }
    __syncthreads();
    for (int i = threadIdx.x; i < nb; i += 256)
        H[(i << NBLK_LOG) + blockIdx.x] = h[i];
}

__global__ __launch_bounds__(256) void scan_h_partial(
        const int* __restrict__ H, int* __restrict__ part, int total) {
    __shared__ int red[4];
    int base = blockIdx.x * SCHUNK + threadIdx.x * 16;
    int s = 0;
    #pragma unroll
    for (int k = 0; k < 16; ++k) { int i = base + k; if (i < total) s += H[i]; }
    #pragma unroll
    for (int off = 32; off >= 1; off >>= 1) s += __shfl_xor(s, off, 64);
    int lane = threadIdx.x & 63, wid = threadIdx.x >> 6;
    if (lane == 0) red[wid] = s;
    __syncthreads();
    if (threadIdx.x == 0) part[blockIdx.x] = red[0] + red[1] + red[2] + red[3];
}

__global__ void scan_h_mid(int* __restrict__ part, int* __restrict__ bbaseN,
                           int nParts, int nE) {
    int tid = threadIdx.x;
    int v = (tid < nParts) ? part[tid] : 0;
    int x = v;
    #pragma unroll
    for (int off = 1; off < 64; off <<= 1) { int y = __shfl_up(x, off, 64); if (tid >= off) x += y; }
    if (tid < nParts) part[tid] = x - v;
    if (tid == 0) bbaseN[0] = nE;
}

__global__ __launch_bounds__(256) void scan_h_final(
        int* __restrict__ H, const int* __restrict__ part,
        int* __restrict__ bbase, int total) {
    __shared__ int wtot[4];
    int tid = threadIdx.x, lane = tid & 63, wid = tid >> 6;
    int base = blockIdx.x * SCHUNK + tid * 16;
    int v[16]; int t = 0;
    #pragma unroll
    for (int k = 0; k < 16; ++k) { int i = base + k; v[k] = (i < total) ? H[i] : 0; t += v[k]; }
    int x = t;
    #pragma unroll
    for (int off = 1; off < 64; off <<= 1) { int y = __shfl_up(x, off, 64); if (lane >= off) x += y; }
    if (lane == 63) wtot[wid] = x;
    __syncthreads();
    int woff = 0;
    for (int w = 0; w < wid; ++w) woff += wtot[w];
    int run = part[blockIdx.x] + woff + (x - t);
    #pragma unroll
    for (int k = 0; k < 16; ++k) {
        int i = base + k;
        if (i < total) {
            H[i] = run;
            if ((i & (NBLK - 1)) == 0) bbase[i >> NBLK_LOG] = run;
            run += v[k];
        }
    }
}

__global__ __launch_bounds__(256) void fill2(
        const void* __restrict__ eidx, const int* __restrict__ flagp,
        const int* __restrict__ H, unsigned long long* __restrict__ pairs,
        int nE, int nb, int epb) {
    __shared__ int cur[MAXB];
    const bool idx64 = (*flagp != 0);
    const int* __restrict__ ei32 = (const int*)eidx;
    const long long* __restrict__ ei64 = (const long long*)eidx;
    for (int i = threadIdx.x; i < nb; i += 256)
        cur[i] = H[(i << NBLK_LOG) + blockIdx.x];
    __syncthreads();
    const int e0 = blockIdx.x * epb;
    const int e1 = min(e0 + epb, nE);
    for (int e = e0 + threadIdx.x; e < e1; e += 256) {
        int s, d;
        if (idx64) { s = (int)ei64[e]; d = (int)ei64[e + nE]; }
        else       { s = ei32[e];      d = ei32[e + nE]; }
        int pos = atomicAdd(&cur[d >> BSHIFT], 1);
        pairs[pos] = (unsigned long long)(unsigned)s
                   | ((unsigned long long)(unsigned)(d & (BN - 1)) << 32);
    }
}

__global__ __launch_bounds__(512) void bucket_to_csr(
        const unsigned long long* __restrict__ pairs,
        const int* __restrict__ bbase,
        int* __restrict__ rowStart, int* __restrict__ srcs,
        int N, int nb, int nE) {
    __shared__ int lcnt[BN];
    __shared__ int lcur[BN];
    __shared__ int wtot[8];
    const int b = blockIdx.x;
    const int base = bbase[b];
    const int cnt  = bbase[b + 1] - base;
    const int tid = threadIdx.x, lane = tid & 63, wid = tid >> 6;
    lcnt[tid] = 0;
    __syncthreads();
    for (int i = tid; i < cnt; i += 512)
        atomicAdd(&lcnt[(int)(pairs[base + i] >> 32)], 1);
    __syncthreads();
    int v = lcnt[tid];
    int x = v;
    #pragma unroll
    for (int off = 1; off < 64; off <<= 1) { int y = __shfl_up(x, off, 64); if (lane >= off) x += y; }
    if (lane == 63) wtot[wid] = x;
    __syncthreads();
    if (tid == 0) {
        int r = 0;
        for (int w = 0; w < 8; ++w) { int t = wtot[w]; wtot[w] = r; r += t; }
    }
    __syncthreads();
    int excl = wtot[wid] + (x - v);
    lcur[tid] = excl;
    int node = b * BN + tid;
    if (node < N) rowStart[node] = base + excl;
    if (b == nb - 1 && tid == 0) rowStart[N] = nE;
    __syncthreads();
    for (int i = tid; i < cnt; i += 512) {
        unsigned long long p = pairs[base + i];
        int pos = atomicAdd(&lcur[(int)(p >> 32)], 1);
        srcs[base + pos] = (int)(unsigned)p;
    }
}

// ---------------- layer stage 1: gather + mean from bf16 features ----------
// 8 lanes per node (lane = 8-feature chunk, 16-B uint4 load), 32 nodes/block.
#define ACC8(v)                                                          \
    do {                                                                 \
        a[0] += __uint_as_float((v).x << 16);                            \
        a[1] += __uint_as_float((v).x & 0xFFFF0000u);                    \
        a[2] += __uint_as_float((v).y << 16);                            \
        a[3] += __uint_as_float((v).y & 0xFFFF0000u);                    \
        a[4] += __uint_as_float((v).z << 16);                            \
        a[5] += __uint_as_float((v).z & 0xFFFF0000u);                    \
        a[6] += __uint_as_float((v).w << 16);                            \
        a[7] += __uint_as_float((v).w & 0xFFFF0000u);                    \
    } while (0)

__global__ __launch_bounds__(256) void gather_mean_bf16(
        const unsigned short* __restrict__ xb,
        const int* __restrict__ rowStart,
        const int* __restrict__ srcs,
        float* __restrict__ agg,
        int nNodes) {
    const int tid = threadIdx.x;
    const int gl = tid & 7;
    const int grp = tid >> 3;
    const int node = blockIdx.x * 32 + grp;
    if (node >= nNodes) return;
    const int r0 = rowStart[node], r1 = rowStart[node + 1];
    float a[8] = {0.f, 0.f, 0.f, 0.f, 0.f, 0.f, 0.f, 0.f};
    int j = r0;
    for (; j + 4 <= r1; j += 4) {
        int s0 = srcs[j], s1 = srcs[j + 1], s2 = srcs[j + 2], s3 = srcs[j + 3];
        uint4 v0 = *(const uint4*)(xb + (size_t)s0 * D + gl * 8);
        uint4 v1 = *(const uint4*)(xb + (size_t)s1 * D + gl * 8);
        uint4 v2 = *(const uint4*)(xb + (size_t)s2 * D + gl * 8);
        uint4 v3 = *(const uint4*)(xb + (size_t)s3 * D + gl * 8);
        ACC8(v0); ACC8(v1); ACC8(v2); ACC8(v3);
    }
    for (; j < r1; ++j) {
        uint4 v = *(const uint4*)(xb + (size_t)srcs[j] * D + gl * 8);
        ACC8(v);
    }
    const float inv = 1.0f / fmaxf((float)(r1 - r0), 1.0f);
    float4 o0, o1;
    o0.x = a[0] * inv; o0.y = a[1] * inv; o0.z = a[2] * inv; o0.w = a[3] * inv;
    o1.x = a[4] * inv; o1.y = a[5] * inv; o1.z = a[6] * inv; o1.w = a[7] * inv;
    *(float4*)&agg[(size_t)node * D + gl * 8] = o0;
    *(float4*)&agg[(size_t)node * D + gl * 8 + 4] = o1;
}

// ---------------- layer stage 2: split-bf16 MFMA GEMM update ----------------
// LAYER 0: self term from f32 x (hi/lo split), out = bf16 + ReLU (to outb).
// LAYER 1: self term from bf16 x1 (hi only), out = f32 + L2-normalize (outf).
template<int LAYER>
__global__ __launch_bounds__(256) void gemm_mfma(
        const float* __restrict__ agg,
        const float* __restrict__ xf,
        const unsigned short* __restrict__ xb,
        const unsigned short* __restrict__ wHi,
        const unsigned short* __restrict__ wLo,
        const float* __restrict__ bl,
        float* __restrict__ outf,
        unsigned short* __restrict__ outb,
        int nNodes, const int* __restrict__ okp) {
    if (!*okp) return;
    const int l = threadIdx.x & 63;
    const int wv = threadIdx.x >> 6;
    const int col = l & 15, grp = l >> 4;
    const int base = blockIdx.x * 64 + wv * 16;
    if (base >= nNodes) return;

    const int anode = min(base + col, nNodes - 1);
    // aggregate frags (f32 -> hi/lo split)
    bf16x8v gH[2], gL[2];
    {
        const float* p = agg + (size_t)anode * D;
        #pragma unroll
        for (int h = 0; h < 2; ++h) {
            const int k0 = h * 32 + grp * 8;
            float4 u0 = *(const float4*)(p + k0);
            float4 u1 = *(const float4*)(p + k0 + 4);
            float v[8] = {u0.x, u0.y, u0.z, u0.w, u1.x, u1.y, u1.z, u1.w};
            #pragma unroll
            for (int j = 0; j < 8; ++j) {
                unsigned short hb = f2bf(v[j]);
                gH[h][j] = (short)hb;
                gL[h][j] = (short)f2bf(v[j] - bf2f(hb));
            }
        }
    }
    // self frags
    bf16x8v sH[2], sL[2];
    if (LAYER == 0) {
        const float* p = xf + (size_t)anode * D;
        #pragma unroll
        for (int h = 0; h < 2; ++h) {
            const int k0 = h * 32 + grp * 8;
            float4 u0 = *(const float4*)(p + k0);
            float4 u1 = *(const float4*)(p + k0 + 4);
            float v[8] = {u0.x, u0.y, u0.z, u0.w, u1.x, u1.y, u1.z, u1.w};
            #pragma unroll
            for (int j = 0; j < 8; ++j) {
                unsigned short hb = f2bf(v[j]);
                sH[h][j] = (short)hb;
                sL[h][j] = (short)f2bf(v[j] - bf2f(hb));
            }
        }
    } else {
        #pragma unroll
        for (int h = 0; h < 2; ++h)
            sH[h] = *(const bf16x8v*)(xb + (size_t)anode * D + h * 32 + grp * 8);
    }

    f32x4v acc[4];
    #pragma unroll
    for (int t = 0; t < 4; ++t) {
        acc[t] = (f32x4v){0.f, 0.f, 0.f, 0.f};
        const unsigned short* whl = wHi + (size_t)(t * 16 + col) * D;
        const unsigned short* wol = wLo + (size_t)(t * 16 + col) * D;
        const unsigned short* whr = whl + 4096;
        const unsigned short* wor = wol + 4096;
        #pragma unroll
        for (int h = 0; h < 2; ++h) {
            const int k0 = h * 32 + grp * 8;
            bf16x8v bh = *(const bf16x8v*)(whl + k0);
            bf16x8v bo = *(const bf16x8v*)(wol + k0);
            acc[t] = __builtin_amdgcn_mfma_f32_16x16x32_bf16(gH[h], bh, acc[t], 0, 0, 0);
            acc[t] = __builtin_amdgcn_mfma_f32_16x16x32_bf16(gL[h], bh, acc[t], 0, 0, 0);
            acc[t] = __builtin_amdgcn_mfma_f32_16x16x32_bf16(gH[h], bo, acc[t], 0, 0, 0);
            bf16x8v bh2 = *(const bf16x8v*)(whr + k0);
            bf16x8v bo2 = *(const bf16x8v*)(wor + k0);
            acc[t] = __builtin_amdgcn_mfma_f32_16x16x32_bf16(sH[h], bh2, acc[t], 0, 0, 0);
            if (LAYER == 0)
                acc[t] = __builtin_amdgcn_mfma_f32_16x16x32_bf16(sL[h], bh2, acc[t], 0, 0, 0);
            acc[t] = __builtin_amdgcn_mfma_f32_16x16x32_bf16(sH[h], bo2, acc[t], 0, 0, 0);
        }
    }

    #pragma unroll
    for (int t = 0; t < 4; ++t) {
        float b = bl[t * 16 + col];
        #pragma unroll
        for (int r = 0; r < 4; ++r) acc[t][r] += b;
    }

    if (LAYER == 0) {
        #pragma unroll
        for (int t = 0; t < 4; ++t)
            #pragma unroll
            for (int r = 0; r < 4; ++r) {
                int n = base + grp * 4 + r;
                if (n < nNodes)
                    outb[(size_t)n * D + t * 16 + col] = f2bf(fmaxf(acc[t][r], 0.f));
            }
    } else {
        float ss[4] = {0.f, 0.f, 0.f, 0.f};
        #pragma unroll
        for (int t = 0; t < 4; ++t)
            #pragma unroll
            for (int r = 0; r < 4; ++r) ss[r] += acc[t][r] * acc[t][r];
        #pragma unroll
        for (int r = 0; r < 4; ++r) {
            #pragma unroll
            for (int off = 1; off < 16; off <<= 1) ss[r] += __shfl_xor(ss[r], off, 64);
        }
        float inv[4];
        #pragma unroll
        for (int r = 0; r < 4; ++r) inv[r] = 1.0f / fmaxf(sqrtf(ss[r]), 1e-12f);
        #pragma unroll
        for (int t = 0; t < 4; ++t)
            #pragma unroll
            for (int r = 0; r < 4; ++r) {
                int n = base + grp * 4 + r;
                if (n < nNodes)
                    outf[(size_t)n * D + t * 16 + col] = acc[t][r] * inv[r];
            }
    }
}

// ---------------- VALU GEMM (runs only if mfma_probe failed) ---------------
template<int LAYER>
__global__ __launch_bounds__(256) void gemm_update(
        const float* __restrict__ agg,
        const float* __restrict__ xf,
        const unsigned short* __restrict__ xb,
        const float* __restrict__ wl,
        const float* __restrict__ bl,
        const float* __restrict__ wr,
        float* __restrict__ outf,
        unsigned short* __restrict__ outb,
        int nNodes, const int* __restrict__ okp) {
    if (*okp) return;   // uniform early-exit before any barrier
    __shared__ float sA[D][GN + 4];
    __shared__ float sW[D][D + 4];
    const int tid = threadIdx.x;
    const int fx = tid & 15, nx = tid >> 4;
    const int f0 = fx * 4, n0 = nx * 8;
    const int nb = blockIdx.x * GN;

    float c[8][4];
    #pragma unroll
    for (int i = 0; i < 8; ++i)
        #pragma unroll
        for (int j = 0; j < 4; ++j) c[i][j] = 0.f;

    #pragma unroll
    for (int phase = 0; phase < 2; ++phase) {
        const float* __restrict__ gW = phase ? wr : wl;
        if (phase) __syncthreads();
        for (int i = tid; i < GN * D; i += 256) {
            int n = i >> 6, k = i & 63;
            int gn = nb + n;
            float val = 0.f;
            if (gn < nNodes) {
                if (phase == 0) val = agg[(size_t)gn * D + k];
                else val = LAYER ? bf2f(xb[(size_t)gn * D + k]) : xf[(size_t)gn * D + k];
            }
            sA[k][n] = val;
        }
        for (int i = tid; i < D * D; i += 256) {
            int f = i >> 6, k = i & 63;
            sW[k][f] = gW[i];
        }
        __syncthreads();
        #pragma unroll 8
        for (int k = 0; k < D; ++k) {
            float4 a0 = *(const float4*)&sA[k][n0];
            float4 a1 = *(const float4*)&sA[k][n0 + 4];
            float4 w  = *(const float4*)&sW[k][f0];
            float av[8] = {a0.x, a0.y, a0.z, a0.w, a1.x, a1.y, a1.z, a1.w};
            float wv[4] = {w.x, w.y, w.z, w.w};
            #pragma unroll
            for (int i = 0; i < 8; ++i)
                #pragma unroll
                for (int j = 0; j < 4; ++j)
                    c[i][j] = fmaf(av[i], wv[j], c[i][j]);
        }
    }

    float4 bv = *(const float4*)&bl[f0];
    float blv[4] = {bv.x, bv.y, bv.z, bv.w};
    #pragma unroll
    for (int i = 0; i < 8; ++i) {
        int gn = nb + n0 + i;
        float o[4];
        #pragma unroll
        for (int j = 0; j < 4; ++j) o[j] = c[i][j] + blv[j];
        if (LAYER == 0) {
            if (gn < nNodes) {
                #pragma unroll
                for (int j = 0; j < 4; ++j)
                    outb[(size_t)gn * D + f0 + j] = f2bf(fmaxf(o[j], 0.f));
            }
        } else {
            float ss = o[0]*o[0] + o[1]*o[1] + o[2]*o[2] + o[3]*o[3];
            #pragma unroll
            for (int off = 8; off >= 1; off >>= 1) ss += __shfl_xor(ss, off, 16);
            float inv = 1.0f / fmaxf(sqrtf(ss), 1e-12f);
            #pragma unroll
            for (int j = 0; j < 4; ++j) o[j] *= inv;
            if (gn < nNodes) {
                float4 ov; ov.x = o[0]; ov.y = o[1]; ov.z = o[2]; ov.w = o[3];
                *(float4*)&outf[(size_t)gn * D + f0] = ov;
            }
        }
    }
}

// ---------------- fallback: atomic scatter path (round-1, known-correct) ----

__global__ __launch_bounds__(256) void sage_scatter(
        const float* __restrict__ x,
        const void* __restrict__ eidx,
        const int* __restrict__ flagp,
        float* __restrict__ agg,
        float* __restrict__ deg,
        int nE, int doDeg) {
    const bool idx64 = (*flagp != 0);
    const int lane = threadIdx.x & 63;
    int wave = (int)((blockIdx.x * blockDim.x + threadIdx.x) >> 6);
    const int waveStride = (int)((gridDim.x * blockDim.x) >> 6);
    const int* __restrict__ ei32 = (const int*)eidx;
    const long long* __restrict__ ei64 = (const long long*)eidx;
    for (int e = wave; e < nE; e += waveStride) {
        int s, d;
        if (idx64) { s = (int)ei64[e]; d = (int)ei64[e + nE]; }
        else       { s = ei32[e];      d = ei32[e + nE]; }
        atomicAdd(&agg[(size_t)d * D + lane], x[(size_t)s * D + lane]);
        if (doDeg && lane == 0) atomicAdd(&deg[d], 1.0f);
    }
}

__global__ __launch_bounds__(256) void sage_update(
        const float* __restrict__ xin,
        const float* __restrict__ agg,
        const float* __restrict__ deg,
        const float* __restrict__ wl,
        const float* __restrict__ bl,
        const float* __restrict__ wr,
        float* __restrict__ xout,
        int nNodes, int mode) {
    __shared__ float wlT[D * D];
    __shared__ float wrT[D * D];
    __shared__ float rowA[4][D];
    __shared__ float rowX[4][D];
    for (int i = threadIdx.x; i < D * D; i += blockDim.x) {
        int f = i >> 6, k = i & 63;
        wlT[k * D + f] = wl[i];
        wrT[k * D + f] = wr[i];
    }
    __syncthreads();
    const int lane = threadIdx.x & 63;
    const int wid = threadIdx.x >> 6;
    const float blv = bl[lane];
    for (int node = blockIdx.x * 4 + wid; node < nNodes; node += gridDim.x * 4) {
        float dg = fmaxf(deg[node], 1.0f);
        float a  = agg[(size_t)node * D + lane] / dg;
        float xv = xin[(size_t)node * D + lane];
        rowA[wid][lane] = a;
        rowX[wid][lane] = xv;
        float acc = blv;
        #pragma unroll
        for (int k = 0; k < D; ++k) {
            acc = fmaf(rowA[wid][k], wlT[k * D + lane], acc);
            acc = fmaf(rowX[wid][k], wrT[k * D + lane], acc);
        }
        if (mode == 0) {
            xout[(size_t)node * D + lane] = fmaxf(acc, 0.0f);
        } else {
            float ss = acc * acc;
            #pragma unroll
            for (int off = 32; off >= 1; off >>= 1) ss += __shfl_xor(ss, off, 64);
            xout[(size_t)node * D + lane] = acc / fmaxf(sqrtf(ss), 1e-12f);
        }
    }
}

extern "C" void kernel_launch(void* const* d_in, const int* in_sizes, int n_in,
                              void* d_out, int out_size, void* d_ws, size_t ws_size,
                              hipStream_t stream) {
    const float* x   = (const float*)d_in[0];
    const float* wl0 = (const float*)d_in[1];
    const float* bl0 = (const float*)d_in[2];
    const float* wr0 = (const float*)d_in[3];
    const float* wl1 = (const float*)d_in[4];
    const float* bl1 = (const float*)d_in[5];
    const float* wr1 = (const float*)d_in[6];
    const void*  ei  = d_in[7];
    float* out = (float*)d_out;

    const int N = in_sizes[0] / D;
    const int E = in_sizes[7] / 2;
    const int NB = (N + BN - 1) / BN;
    const int EPB = (E + NBLK - 1) / NBLK;
    const int TOTAL = NB << NBLK_LOG;
    const int NPARTS = (TOTAL + SCHUNK - 1) / SCHUNK;

    char* ws = (char*)d_ws;
    size_t off = 0;
    auto alloc = [&](size_t bytes) { void* p = ws + off; off = (off + bytes + 255) & ~(size_t)255; return p; };

    // regionA serves (in strict temporal order): pairs [fill2->b2csr],
    // xb [conv_xbf->gather0], x1b [gemm0->gemm1].
    size_t regionA_bytes = (size_t)E * 8;
    if ((size_t)N * D * 2 > regionA_bytes) regionA_bytes = (size_t)N * D * 2;
    size_t need = 0;
    {
        size_t o = 0;
        auto sim = [&](size_t b) { o = (o + b + 255) & ~(size_t)255; };
        sim(4); sim(4); sim(16384 * 2); sim(16384 * 2);
        sim(((size_t)MAXB << NBLK_LOG) * 4); sim(64 * 4); sim(((size_t)MAXB + 1) * 4);
        sim(((size_t)N + 1) * 4); sim((size_t)E * 4);
        sim(regionA_bytes); sim((size_t)N * D * 4);
        need = o;
    }

    if (ws_size >= need && NB <= MAXB && NPARTS <= 64) {
        int* flag     = (int*)alloc(4);
        int* okf      = (int*)alloc(4);
        unsigned short* whi = (unsigned short*)alloc(16384 * 2);
        unsigned short* wlo = (unsigned short*)alloc(16384 * 2);
        int* H        = (int*)alloc(((size_t)MAXB << NBLK_LOG) * 4);
        int* part     = (int*)alloc(64 * 4);
        int* bbase    = (int*)alloc(((size_t)MAXB + 1) * 4);
        int* rowStart = (int*)alloc(((size_t)N + 1) * 4);
        int* srcs     = (int*)alloc((size_t)E * 4);
        void* regionA = alloc(regionA_bytes);
        float* agg    = (float*)alloc((size_t)N * D * 4);
        unsigned long long* pairs = (unsigned long long*)regionA;
        unsigned short* xb  = (unsigned short*)regionA;   // layer-0 bf16 features
        unsigned short* x1b = (unsigned short*)regionA;   // layer-0 output (bf16)

        detect_idx64<<<1, 64, 0, stream>>>((const int*)ei, flag);
        mfma_probe<<<1, 64, 0, stream>>>(okf);
        conv_w4<<<64, 256, 0, stream>>>(wl0, wr0, wl1, wr1, whi, wlo);
        hist2d<<<NBLK, 256, 0, stream>>>(ei, flag, H, E, NB, EPB);
        scan_h_partial<<<NPARTS, 256, 0, stream>>>(H, part, TOTAL);
        scan_h_mid<<<1, 64, 0, stream>>>(part, &bbase[NB], NPARTS, E);
        scan_h_final<<<NPARTS, 256, 0, stream>>>(H, part, bbase, TOTAL);
        fill2<<<NBLK, 256, 0, stream>>>(ei, flag, H, pairs, E, NB, EPB);
        bucket_to_csr<<<NB, 512, 0, stream>>>(pairs, bbase, rowStart, srcs, N, NB, E);
        conv_xbf<<<1024, 256, 0, stream>>>(x, (uint4*)xb, N * 8);   // after b2csr: regionA reuse

        const int gGather = (N + 31) / 32;
        const int gMfma   = (N + 63) / 64;
        const int gGemm   = (N + GN - 1) / GN;
        gather_mean_bf16<<<gGather, 256, 0, stream>>>(xb, rowStart, srcs, agg, N);
        gemm_mfma<0><<<gMfma, 256, 0, stream>>>(agg, x, (const unsigned short*)0,
                                                whi, wlo, bl0, (float*)0, x1b, N, okf);
        gemm_update<0><<<gGemm, 256, 0, stream>>>(agg, x, (const unsigned short*)0,
                                                  wl0, bl0, wr0, (float*)0, x1b, N, okf);
        gather_mean_bf16<<<gGather, 256, 0, stream>>>(x1b, rowStart, srcs, agg, N);
        gemm_mfma<1><<<gMfma, 256, 0, stream>>>(agg, (const float*)0, x1b,
                                                whi + 2 * 4096, wlo + 2 * 4096, bl1,
                                                out, (unsigned short*)0, N, okf);
        gemm_update<1><<<gGemm, 256, 0, stream>>>(agg, (const float*)0, x1b,
                                                  wl1, bl1, wr1, out, (unsigned short*)0, N, okf);
    } else {
        // fallback: round-1 scatter path (~26 MB ws)
        int*   flag = (int*)alloc(4);
        float* deg  = (float*)alloc((size_t)N * 4);
        float* agg  = (float*)alloc((size_t)N * D * 4);
        float* x1   = out;  // safe: sage_update reads only its own row of xin

        detect_idx64<<<1, 64, 0, stream>>>((const int*)ei, flag);
        hipMemsetAsync(deg, 0, ((size_t)N + (size_t)N * D) * 4, stream);
        sage_scatter<<<4096, 256, 0, stream>>>(x, ei, flag, agg, deg, E, 1);
        sage_update<<<2048, 256, 0, stream>>>(x, agg, deg, wl0, bl0, wr0, x1, N, 0);
        hipMemsetAsync(agg, 0, (size_t)N * D * 4, stream);
        sage_scatter<<<4096, 256, 0, stream>>>(x1, ei, flag, agg, deg, E, 0);
        sage_update<<<2048, 256, 0, stream>>>(x1, agg, deg, wl1, bl1, wr1, out, N, 1);
    }
}